// Round 3
// baseline (631.012 us; speedup 1.0000x reference)
//
#include <hip/hip_runtime.h>
#include <hip/hip_bf16.h>
#include <math.h>

#define NPTS 40000
#define KNB 16
#define CH 128

typedef unsigned short u16;
typedef __attribute__((ext_vector_type(8))) short bf16x8;
typedef __attribute__((ext_vector_type(4))) float f32x4;

__device__ __forceinline__ float gelu_f(float v) {
  float u = 0.7978845608028654f * (v + 0.044715f * v * v * v);
  return 0.5f * v * (1.0f + tanhf(u));
}

__device__ __forceinline__ float bnscale(float g) {
  return g * rsqrtf(1.0f + 1e-5f);
}

__device__ __forceinline__ u16 f2bf(float x) {
  union { __hip_bfloat16 b; u16 u; } cv;
  cv.b = __float2bfloat16(x);
  return cv.u;
}

__device__ __forceinline__ float bf2f(u16 u) {
  union { float f; unsigned int i; } cv;
  cv.i = ((unsigned int)u) << 16;
  return cv.f;
}

__device__ __forceinline__ void bf16split(float x, u16& hi, u16& lo) {
  hi = f2bf(x);
  lo = f2bf(x - bf2f(hi));
}

// async global->LDS: 16B/lane, wave-uniform LDS base + lane*16
__device__ __forceinline__ void gl2lds(const u16* gp, u16* lp) {
  __builtin_amdgcn_global_load_lds(
      (const __attribute__((address_space(1))) void*)gp,
      (__attribute__((address_space(3))) void*)lp, 16, 0, 0);
}

// stage a [128 rows][128 u16] tile (32 KB), LDS linear; global already swizzled
__device__ __forceinline__ void stage128(u16* lds, const u16* __restrict__ g,
                                         int gstride, int t) {
  const int w = t >> 6, lane = t & 63;
#pragma unroll
  for (int i = 0; i < 2048; i += 256) {
    const int wc0 = i + w * 64;      // wave-uniform chunk base
    const int c = wc0 + lane;        // this lane's 16B chunk
    gl2lds(g + (size_t)(c >> 4) * gstride + (c & 15) * 8, lds + wc0 * 8);
  }
}

// swizzled W-fragment read: element (nrow, chunk*8..+7) of staged tile
__device__ __forceinline__ bf16x8 ldw(const u16* lds, int nrow, int chunk) {
  return *(const bf16x8*)(lds + nrow * 128 + ((chunk ^ (nrow & 7)) << 3));
}

// ---------------- knn_spse_4 + BN0 -> bf16 hi/lo ----------------
__global__ __launch_bounds__(128) void spse_kernel(
    const float* __restrict__ x, const float* __restrict__ xyz,
    const int* __restrict__ knn, const float* __restrict__ sm,
    const float* __restrict__ sc, const float* __restrict__ sh,
    const float* __restrict__ g0, const float* __restrict__ b0,
    u16* __restrict__ oh, u16* __restrict__ ol) {
  const int n = blockIdx.x;
  const int c = threadIdx.x;
  __shared__ float sr[KNB][3];
  __shared__ float sf[KNB][4];
  if (c < KNB) {
    const int j = knn[n * KNB + c];
    sr[c][0] = xyz[j * 3 + 0] - xyz[n * 3 + 0];
    sr[c][1] = xyz[j * 3 + 1] - xyz[n * 3 + 1];
    sr[c][2] = xyz[j * 3 + 2] - xyz[n * 3 + 2];
    float f0 = x[j * 4 + 0] - x[n * 4 + 0];
    float f1 = x[j * 4 + 1] - x[n * 4 + 1];
    float f2 = x[j * 4 + 2] - x[n * 4 + 2];
    float f3 = x[j * 4 + 3] - x[n * 4 + 3];
    sf[c][0] = f0 * f0; sf[c][1] = f1 * f1;
    sf[c][2] = f2 * f2; sf[c][3] = f3 * f3;
  }
  __syncthreads();
  const float m0 = sm[c], m1 = sm[CH + c], m2 = sm[2 * CH + c];
  const float m4 = sm[4 * CH + c], m5 = sm[5 * CH + c], m6 = sm[6 * CH + c];
  const float m8 = sm[8 * CH + c], m9 = sm[9 * CH + c], m10 = sm[10 * CH + c];
  float c0 = sc[c];          c0 *= c0;
  float c1 = sc[CH + c];     c1 *= c1;
  float c2 = sc[2 * CH + c]; c2 *= c2;
  float h2 = sh[c];          h2 *= h2;
  float e = 0.0f;
#pragma unroll
  for (int k = 0; k < KNB; k++) {
    const float r0 = sr[k][0], r1 = sr[k][1], r2 = sr[k][2];
    const float d0 = fmaf(r2, m2, fmaf(r1, m1, r0 * m0));
    const float d1 = fmaf(r2, m6, fmaf(r1, m5, r0 * m4));
    const float d2 = fmaf(r2, m10, fmaf(r1, m9, r0 * m8));
    e = fmaf(d0, d0, e);
    e = fmaf(d1, d1, e);
    e = fmaf(d2, d2, e);
    e = fmaf(sf[k][0], c0, e);
    e = fmaf(sf[k][1], c1, e);
    e = fmaf(sf[k][2], c2, e);
    e = fmaf(sf[k][3], h2, e);
  }
  const float v = sqrtf(e * (1.0f / KNB)) * bnscale(g0[c]) + b0[c];
  u16 hi, lo; bf16split(v, hi, lo);
  const size_t idx = (size_t)n * CH + c;
  oh[idx] = hi; ol[idx] = lo;
}

// ---------------- LFP gather + PE + max + BN + residual ----------------
// 128 thr = 4 points, 32 lanes/point, 4 ch/thread (one D4 group), float4 gathers
__global__ __launch_bounds__(128) void lfp_kernel(
    const float* __restrict__ xp, const int* __restrict__ knn,
    const float* __restrict__ xyz, const float* __restrict__ coor,
    const float* __restrict__ scale, const float* __restrict__ g,
    const float* __restrict__ b, float* __restrict__ hf,
    u16* __restrict__ hh, u16* __restrict__ hl) {
  const int t = threadIdx.x;
  const int bid = blockIdx.x;
  __shared__ int si[4][KNB];
  __shared__ float sr[4][KNB][3];
  if (t < 64) {
    const int pp = t >> 4, kk = t & 15;
    const int n = bid * 4 + pp;
    const int j = knn[n * KNB + kk];
    si[pp][kk] = j;
    sr[pp][kk][0] = xyz[j * 3 + 0] - xyz[n * 3 + 0];
    sr[pp][kk][1] = xyz[j * 3 + 1] - xyz[n * 3 + 1];
    sr[pp][kk][2] = xyz[j * 3 + 2] - xyz[n * 3 + 2];
  }
  __syncthreads();
  const int p = t >> 5, d = t & 31;
  const int n = bid * 4 + p;
  const float c0 = coor[d], c1 = coor[32 + d], c2 = coor[64 + d];
  float s2 = scale[d]; s2 *= s2;
  float a0 = -3.0e38f, a1 = -3.0e38f, a2 = -3.0e38f, a3 = -3.0e38f;
#pragma unroll
  for (int k = 0; k < KNB; k++) {
    const int j = si[p][k];
    const float pe = fmaf(sr[p][k][2], c2, fmaf(sr[p][k][1], c1, sr[p][k][0] * c0)) * s2;
    const float4 v = *(const float4*)(xp + (size_t)j * CH + d * 4);
    a0 = fmaxf(a0, v.x + pe);
    a1 = fmaxf(a1, v.y + pe);
    a2 = fmaxf(a2, v.z + pe);
    a3 = fmaxf(a3, v.w + pe);
  }
  const size_t off = (size_t)n * CH + d * 4;
  const float4 gg = *(const float4*)(g + d * 4);
  const float4 bb = *(const float4*)(b + d * 4);
  const float4 ho = *(const float4*)(hf + off);
  float4 nv;
  nv.x = ho.x + a0 * bnscale(gg.x) + bb.x;
  nv.y = ho.y + a1 * bnscale(gg.y) + bb.y;
  nv.z = ho.z + a2 * bnscale(gg.z) + bb.z;
  nv.w = ho.w + a3 * bnscale(gg.w) + bb.w;
  *(float4*)(hf + off) = nv;
  union { u16 a[4]; uint2 v; } ph, pl;
  u16 hi, lo;
  bf16split(nv.x, hi, lo); ph.a[0] = hi; pl.a[0] = lo;
  bf16split(nv.y, hi, lo); ph.a[1] = hi; pl.a[1] = lo;
  bf16split(nv.z, hi, lo); ph.a[2] = hi; pl.a[2] = lo;
  bf16split(nv.w, hi, lo); ph.a[3] = hi; pl.a[3] = lo;
  *(uint2*)(hh + off) = ph.v;
  *(uint2*)(hl + off) = pl.v;
}

// ---------------- weight prep: transpose + bf16 hi/lo + XOR-swizzle ----------------
// dst layout (u16): nw1@0 [256][128], nw2@32768 [128][256], mw1[j]@65536+j*65536 [512][128],
// mw2[j]@262144+j*65536 [128][512], lproj[i]@458752+i*16384 [128][128], post@524288 [256][128]
// element (n,k) stored at n*Kd + ((k&~127) | ((k&127) ^ ((n&7)<<3)))
__global__ __launch_bounds__(256) void prep_weights(
    const float* __restrict__ nw1, const float* __restrict__ nw2,
    const float* __restrict__ mw1, const float* __restrict__ mw2,
    const float* __restrict__ lproj, const float* __restrict__ pw,
    const float* __restrict__ pg, u16* __restrict__ th, u16* __restrict__ tl) {
  const int idx = blockIdx.x * 256 + threadIdx.x;
  const float* src;
  int local, Kd, Nd, dst;
  float scale = 1.0f;
  if (idx < 32768)        { src = nw1; local = idx;          Kd = 128; Nd = 256; dst = 0; }
  else if (idx < 65536)   { src = nw2; local = idx - 32768;  Kd = 256; Nd = 128; dst = 32768; }
  else if (idx < 262144)  { int j = (idx - 65536) >> 16;  local = (idx - 65536) & 65535;
                            src = mw1 + j * 65536; Kd = 128; Nd = 512; dst = 65536 + j * 65536; }
  else if (idx < 458752)  { int j = (idx - 262144) >> 16; local = (idx - 262144) & 65535;
                            src = mw2 + j * 65536; Kd = 512; Nd = 128; dst = 262144 + j * 65536; }
  else if (idx < 524288)  { int i = (idx - 458752) >> 14; local = (idx - 458752) & 16383;
                            src = lproj + i * 16384; Kd = 128; Nd = 128; dst = 458752 + i * 16384; }
  else if (idx < 557056)  { local = idx - 524288; src = pw; Kd = 128; Nd = 256; dst = 524288;
                            scale = bnscale(pg[local >> 8]); }
  else return;
  const int k = local / Nd, n = local % Nd;
  const float v = src[local] * scale;
  u16 hi, lo; bf16split(v, hi, lo);
  const int ks = (k & ~127) | ((k & 127) ^ ((n & 7) << 3));
  const int o = dst + n * Kd + ks;
  th[o] = hi; tl[o] = lo;
}

// folded post bias: fb[n] = sum_k pb[k] * pw[k][n]
__global__ __launch_bounds__(256) void fold_pb(const float* __restrict__ pw,
                                               const float* __restrict__ pb,
                                               float* __restrict__ fb) {
  const int t = threadIdx.x;
  float a = 0.0f;
  for (int k = 0; k < 128; k++) a = fmaf(pb[k], pw[k * 256 + t], a);
  fb[t] = a;
}

// ---------------- fused MLP: h' = [h +] BN(gelu(h@W1+b1)@W2) ----------------
// BM=64 rows/block, 4 waves (2x2), A (K=128) in registers direct from global,
// weight slabs through LDS (pre-swizzled), hid chunk in LDS (bf16-hi, swizzled).
template <int HID, bool RES>
__global__ __launch_bounds__(256, 2) void fused_mlp(
    const u16* Ahi, const u16* Alo,
    const u16* __restrict__ W1h, const u16* __restrict__ W1l,
    const u16* __restrict__ W2h, const u16* __restrict__ W2l,
    const float* __restrict__ b1, const float* __restrict__ g,
    const float* __restrict__ bb, float* hf, u16* hh, u16* hl) {
  __shared__ __align__(16) u16 Wh_s[128 * 128];
  __shared__ __align__(16) u16 Wl_s[128 * 128];
  __shared__ __align__(16) u16 hid[64 * 128];
  const int t = threadIdx.x;
  const int lane = t & 63;
  const int w = t >> 6;
  const int row0 = blockIdx.x * 64;
  const int wm0 = (w >> 1) * 32;
  const int wn0 = (w & 1) * 64;
  const int lc = lane & 15;
  const int lq = lane >> 4;
  const int lq4 = lq * 4, lq8 = lq * 8;

  // A fragments: rows of this wave, all K=128, hi+lo (reg-resident whole kernel)
  bf16x8 ah[2][4], al[2][4];
#pragma unroll
  for (int mf = 0; mf < 2; mf++)
#pragma unroll
    for (int ks = 0; ks < 4; ks++) {
      const size_t ao = (size_t)(row0 + wm0 + mf * 16 + lc) * 128 + ks * 32 + lq8;
      ah[mf][ks] = *(const bf16x8*)(Ahi + ao);
      al[mf][ks] = *(const bf16x8*)(Alo + ao);
    }

  const f32x4 zz = {0.0f, 0.0f, 0.0f, 0.0f};
  f32x4 acc[2][4];
#pragma unroll
  for (int mf = 0; mf < 2; mf++)
#pragma unroll
    for (int nf = 0; nf < 4; nf++) acc[mf][nf] = zz;

#pragma unroll 1
  for (int s = 0; s < HID / 128; s++) {
    if (s) __syncthreads();
    stage128(Wh_s, W1h + s * 16384, 128, t);
    stage128(Wl_s, W1l + s * 16384, 128, t);
    __syncthreads();
    // ---- w1-phase: acc1 = A @ W1slab (3-MFMA split) ----
    f32x4 acc1[2][4];
#pragma unroll
    for (int mf = 0; mf < 2; mf++)
#pragma unroll
      for (int nf = 0; nf < 4; nf++) acc1[mf][nf] = zz;
#pragma unroll
    for (int ks = 0; ks < 4; ks++) {
      const int chunk = ks * 4 + lq;
      bf16x8 bh[4], bl[4];
#pragma unroll
      for (int nf = 0; nf < 4; nf++) {
        const int nr = wn0 + nf * 16 + lc;
        bh[nf] = ldw(Wh_s, nr, chunk);
        bl[nf] = ldw(Wl_s, nr, chunk);
      }
#pragma unroll
      for (int mf = 0; mf < 2; mf++)
#pragma unroll
        for (int nf = 0; nf < 4; nf++) {
          acc1[mf][nf] = __builtin_amdgcn_mfma_f32_16x16x32_bf16(ah[mf][ks], bh[nf], acc1[mf][nf], 0, 0, 0);
          acc1[mf][nf] = __builtin_amdgcn_mfma_f32_16x16x32_bf16(ah[mf][ks], bl[nf], acc1[mf][nf], 0, 0, 0);
          acc1[mf][nf] = __builtin_amdgcn_mfma_f32_16x16x32_bf16(al[mf][ks], bh[nf], acc1[mf][nf], 0, 0, 0);
        }
    }
    // ---- bias + gelu -> hid (bf16-hi, XOR-swizzled) ----
    float b1v[4];
#pragma unroll
    for (int nf = 0; nf < 4; nf++) b1v[nf] = b1[s * 128 + wn0 + nf * 16 + lc];
#pragma unroll
    for (int mf = 0; mf < 2; mf++)
#pragma unroll
      for (int nf = 0; nf < 4; nf++) {
        const int col_l = wn0 + nf * 16 + lc;
#pragma unroll
        for (int q = 0; q < 4; q++) {
          const int row_l = wm0 + mf * 16 + lq4 + q;
          const float v = gelu_f(acc1[mf][nf][q] + b1v[nf]);
          hid[row_l * 128 + (((col_l >> 3) ^ (row_l & 7)) << 3) + (col_l & 7)] = f2bf(v);
        }
      }
    __syncthreads();
    stage128(Wh_s, W2h + s * 128, HID, t);
    stage128(Wl_s, W2l + s * 128, HID, t);
    __syncthreads();
    // ---- w2-phase: acc += hid @ W2slab (2-MFMA split) ----
#pragma unroll
    for (int ks = 0; ks < 4; ks++) {
      const int chunk = ks * 4 + lq;
      bf16x8 ha[2];
#pragma unroll
      for (int mf = 0; mf < 2; mf++) {
        const int rr = wm0 + mf * 16 + lc;
        ha[mf] = *(const bf16x8*)(hid + rr * 128 + ((chunk ^ (rr & 7)) << 3));
      }
      bf16x8 bh[4], bl[4];
#pragma unroll
      for (int nf = 0; nf < 4; nf++) {
        const int nr = wn0 + nf * 16 + lc;
        bh[nf] = ldw(Wh_s, nr, chunk);
        bl[nf] = ldw(Wl_s, nr, chunk);
      }
#pragma unroll
      for (int mf = 0; mf < 2; mf++)
#pragma unroll
        for (int nf = 0; nf < 4; nf++) {
          acc[mf][nf] = __builtin_amdgcn_mfma_f32_16x16x32_bf16(ha[mf], bh[nf], acc[mf][nf], 0, 0, 0);
          acc[mf][nf] = __builtin_amdgcn_mfma_f32_16x16x32_bf16(ha[mf], bl[nf], acc[mf][nf], 0, 0, 0);
        }
    }
  }

  // ---- epilogue: BN (+residual), write h fp32 + hi/lo ----
  float S0[4], S1[4];
#pragma unroll
  for (int nf = 0; nf < 4; nf++) {
    const int col = wn0 + nf * 16 + lc;
    S0[nf] = bnscale(g[col]);
    S1[nf] = bb[col];
  }
#pragma unroll
  for (int mf = 0; mf < 2; mf++)
#pragma unroll
    for (int q = 0; q < 4; q++) {
      const int r = row0 + wm0 + mf * 16 + lq4 + q;
#pragma unroll
      for (int nf = 0; nf < 4; nf++) {
        const int col = wn0 + nf * 16 + lc;
        const size_t off = (size_t)r * CH + col;
        float v = acc[mf][nf][q] * S0[nf] + S1[nf];
        if (RES) v += hf[off];
        hf[off] = v;
        u16 hi, lo; bf16split(v, hi, lo);
        hh[off] = hi; hl[off] = lo;
      }
    }
}

// ---------------- single-stage K=128 GEMM (lproj / postproj) ----------------
// out[M x ostride块] = A(hi/lo regs) @ W(128-col block, staged once) [+ bias]
template <bool BIAS>
__global__ __launch_bounds__(256, 2) void gemm_k128(
    const u16* __restrict__ Ahi, const u16* __restrict__ Alo,
    const u16* __restrict__ Wh_g, const u16* __restrict__ Wl_g,
    const float* __restrict__ bias, float* __restrict__ outf, int ostride) {
  __shared__ __align__(16) u16 Wh_s[128 * 128];
  __shared__ __align__(16) u16 Wl_s[128 * 128];
  const int t = threadIdx.x;
  const int lane = t & 63;
  const int w = t >> 6;
  const int row0 = blockIdx.x * 64;
  const int col0 = blockIdx.y * 128;
  const int wm0 = (w >> 1) * 32;
  const int wn0 = (w & 1) * 64;
  const int lc = lane & 15;
  const int lq = lane >> 4;
  const int lq4 = lq * 4, lq8 = lq * 8;

  stage128(Wh_s, Wh_g + (size_t)blockIdx.y * 16384, 128, t);
  stage128(Wl_s, Wl_g + (size_t)blockIdx.y * 16384, 128, t);

  bf16x8 ah[2][4], al[2][4];
#pragma unroll
  for (int mf = 0; mf < 2; mf++)
#pragma unroll
    for (int ks = 0; ks < 4; ks++) {
      const size_t ao = (size_t)(row0 + wm0 + mf * 16 + lc) * 128 + ks * 32 + lq8;
      ah[mf][ks] = *(const bf16x8*)(Ahi + ao);
      al[mf][ks] = *(const bf16x8*)(Alo + ao);
    }
  const f32x4 zz = {0.0f, 0.0f, 0.0f, 0.0f};
  f32x4 acc[2][4];
#pragma unroll
  for (int mf = 0; mf < 2; mf++)
#pragma unroll
    for (int nf = 0; nf < 4; nf++) acc[mf][nf] = zz;

  __syncthreads();
#pragma unroll
  for (int ks = 0; ks < 4; ks++) {
    const int chunk = ks * 4 + lq;
    bf16x8 bh[4], bl[4];
#pragma unroll
    for (int nf = 0; nf < 4; nf++) {
      const int nr = wn0 + nf * 16 + lc;
      bh[nf] = ldw(Wh_s, nr, chunk);
      bl[nf] = ldw(Wl_s, nr, chunk);
    }
#pragma unroll
    for (int mf = 0; mf < 2; mf++)
#pragma unroll
      for (int nf = 0; nf < 4; nf++) {
        acc[mf][nf] = __builtin_amdgcn_mfma_f32_16x16x32_bf16(ah[mf][ks], bh[nf], acc[mf][nf], 0, 0, 0);
        acc[mf][nf] = __builtin_amdgcn_mfma_f32_16x16x32_bf16(ah[mf][ks], bl[nf], acc[mf][nf], 0, 0, 0);
        acc[mf][nf] = __builtin_amdgcn_mfma_f32_16x16x32_bf16(al[mf][ks], bh[nf], acc[mf][nf], 0, 0, 0);
      }
  }

  float bv[4];
#pragma unroll
  for (int nf = 0; nf < 4; nf++)
    bv[nf] = BIAS ? bias[col0 + wn0 + nf * 16 + lc] : 0.0f;
#pragma unroll
  for (int mf = 0; mf < 2; mf++)
#pragma unroll
    for (int q = 0; q < 4; q++) {
      const int r = row0 + wm0 + mf * 16 + lq4 + q;
#pragma unroll
      for (int nf = 0; nf < 4; nf++) {
        const int col = col0 + wn0 + nf * 16 + lc;
        outf[(size_t)r * ostride + col] = acc[mf][nf][q] + bv[nf];
      }
    }
}

extern "C" void kernel_launch(void* const* d_in, const int* in_sizes, int n_in,
                              void* d_out, int out_size, void* d_ws, size_t ws_size,
                              hipStream_t stream) {
  const float* x    = (const float*)d_in[0];
  const float* xyz  = (const float*)d_in[1];
  const int*   knn  = (const int*)d_in[2];
  const float* sm   = (const float*)d_in[3];
  const float* scc  = (const float*)d_in[4];
  const float* shh  = (const float*)d_in[5];
  const float* bn0g = (const float*)d_in[6];
  const float* bn0b = (const float*)d_in[7];
  const float* nw1  = (const float*)d_in[8];
  const float* nb1  = (const float*)d_in[9];
  const float* nw2  = (const float*)d_in[10];
  const float* nbng = (const float*)d_in[11];
  const float* nbnb = (const float*)d_in[12];
  const float* lproj  = (const float*)d_in[13];
  const float* lcoor  = (const float*)d_in[14];
  const float* lscale = (const float*)d_in[15];
  const float* lbng   = (const float*)d_in[16];
  const float* lbnb   = (const float*)d_in[17];
  const float* mw1  = (const float*)d_in[18];
  const float* mb1  = (const float*)d_in[19];
  const float* mw2  = (const float*)d_in[20];
  const float* mbng = (const float*)d_in[21];
  const float* mbnb = (const float*)d_in[22];
  const float* pg   = (const float*)d_in[23];
  const float* pb   = (const float*)d_in[24];
  const float* pw   = (const float*)d_in[25];
  float* out = (float*)d_out;

  // workspace (bytes)
  char* ws = (char*)d_ws;
  float* h    = (float*)(ws + 0);            // 40000*128*4 = 20,480,000
  u16*   h_hi = (u16*)(ws + 20480000);       // 10,240,000
  u16*   h_lo = (u16*)(ws + 30720000);       // 10,240,000
  float* xp   = (float*)(ws + 40960000);     // 20,480,000
  u16*   Wh   = (u16*)(ws + 61440000);       // 1,114,112
  u16*   Wl   = (u16*)(ws + 62554112);       // 1,114,112
  float* fb   = (float*)(ws + 63668224);     // 1,024

  const u16* nw1t   = Wh + 0;
  const u16* nw2t   = Wh + 32768;
  const u16* mw1t   = Wh + 65536;
  const u16* mw2t   = Wh + 262144;
  const u16* lprojt = Wh + 458752;
  const u16* postt  = Wh + 524288;
  const u16* nw1tl   = Wl + 0;
  const u16* nw2tl   = Wl + 32768;
  const u16* mw1tl   = Wl + 65536;
  const u16* mw2tl   = Wl + 262144;
  const u16* lprojtl = Wl + 458752;
  const u16* posttl  = Wl + 524288;

  prep_weights<<<2176, 256, 0, stream>>>(nw1, nw2, mw1, mw2, lproj, pw, pg, Wh, Wl);
  fold_pb<<<1, 256, 0, stream>>>(pw, pb, fb);

  spse_kernel<<<NPTS, 128, 0, stream>>>(x, xyz, knn, sm, scc, shh, bn0g, bn0b, h_hi, h_lo);

  // nbr_proj + nbr_bn (no residual): h = BN(gelu(nbr@w1+b1)@w2)
  fused_mlp<256, false><<<625, 256, 0, stream>>>(
      h_hi, h_lo, nw1t, nw1tl, nw2t, nw2tl, nb1, nbng, nbnb, h, h_hi, h_lo);
  // mlp 0 (residual)
  fused_mlp<512, true><<<625, 256, 0, stream>>>(
      h_hi, h_lo, mw1t, mw1tl, mw2t, mw2tl, mb1, mbng, mbnb, h, h_hi, h_lo);

  for (int i = 0; i < 4; i++) {
    gemm_k128<false><<<dim3(625, 1), 256, 0, stream>>>(
        h_hi, h_lo, lprojt + i * 16384, lprojtl + i * 16384, nullptr, xp, 128);
    lfp_kernel<<<10000, 128, 0, stream>>>(xp, knn, xyz, lcoor + i * 96, lscale + i * 32,
                                          lbng + i * 128, lbnb + i * 128, h, h_hi, h_lo);
    if (i & 1) {
      const int j = i / 2 + 1;
      fused_mlp<512, true><<<625, 256, 0, stream>>>(
          h_hi, h_lo, mw1t + j * 65536, mw1tl + j * 65536, mw2t + j * 65536,
          mw2tl + j * 65536, mb1 + j * 512, mbng + j * 128, mbnb + j * 128, h, h_hi, h_lo);
    }
  }

  // postproj (BN folded into weights at prep; rank-1 bias from fold_pb)
  gemm_k128<true><<<dim3(625, 2), 256, 0, stream>>>(
      h_hi, h_lo, postt, posttl, fb, out, 256);
}

// Round 4
// 550.286 us; speedup vs baseline: 1.1467x; 1.1467x over previous
//
#include <hip/hip_runtime.h>
#include <hip/hip_bf16.h>
#include <math.h>

#define NPTS 40000
#define KNB 16
#define CH 128

typedef unsigned short u16;
typedef __attribute__((ext_vector_type(8))) short bf16x8;
typedef __attribute__((ext_vector_type(4))) float f32x4;

__device__ __forceinline__ float gelu_f(float v) {
  float u = 0.7978845608028654f * (v + 0.044715f * v * v * v);
  return 0.5f * v * (1.0f + tanhf(u));
}

__device__ __forceinline__ float bnscale(float g) {
  return g * rsqrtf(1.0f + 1e-5f);
}

__device__ __forceinline__ u16 f2bf(float x) {
  union { __hip_bfloat16 b; u16 u; } cv;
  cv.b = __float2bfloat16(x);
  return cv.u;
}

__device__ __forceinline__ float bf2f(u16 u) {
  union { float f; unsigned int i; } cv;
  cv.i = ((unsigned int)u) << 16;
  return cv.f;
}

__device__ __forceinline__ void bf16split(float x, u16& hi, u16& lo) {
  hi = f2bf(x);
  lo = f2bf(x - bf2f(hi));
}

// async global->LDS: 16B/lane, wave-uniform LDS base + lane*16
__device__ __forceinline__ void gl2lds(const u16* gp, u16* lp) {
  __builtin_amdgcn_global_load_lds(
      (const __attribute__((address_space(1))) void*)gp,
      (__attribute__((address_space(3))) void*)lp, 16, 0, 0);
}

// stage [ROWS][32 u16] tile (64B rows) from g[grow0..][gcol0..+31], LDS linear
template <int ROWS>
__device__ __forceinline__ void stage_rows(u16* lds, const u16* __restrict__ g,
                                           int gstride, int grow0, int gcol0, int t) {
  const int w = t >> 6, lane = t & 63;
#pragma unroll
  for (int i = 0; i < ROWS * 4; i += 256) {
    const int wc0 = i + w * 64;   // wave-uniform chunk base
    const int c = wc0 + lane;     // this lane's 16B chunk
    gl2lds(g + (size_t)(grow0 + (c >> 2)) * gstride + gcol0 + (c & 3) * 8,
           lds + wc0 * 8);
  }
}

// stage a [128][128 u16] tile (32 KB), LDS linear; global already swizzled
__device__ __forceinline__ void stage128(u16* lds, const u16* __restrict__ g, int t) {
  const int w = t >> 6, lane = t & 63;
#pragma unroll
  for (int i = 0; i < 2048; i += 256) {
    const int wc0 = i + w * 64;
    const int c = wc0 + lane;
    gl2lds(g + (size_t)(c >> 4) * 128 + (c & 15) * 8, lds + wc0 * 8);
  }
}

// 128-swizzled W-fragment read (k128 path)
__device__ __forceinline__ bf16x8 ldw(const u16* lds, int nrow, int chunk) {
  return *(const bf16x8*)(lds + nrow * 128 + ((chunk ^ (nrow & 7)) << 3));
}

// ---------------- knn_spse_4 + BN0 -> bf16 hi/lo ----------------
__global__ __launch_bounds__(128) void spse_kernel(
    const float* __restrict__ x, const float* __restrict__ xyz,
    const int* __restrict__ knn, const float* __restrict__ sm,
    const float* __restrict__ sc, const float* __restrict__ sh,
    const float* __restrict__ g0, const float* __restrict__ b0,
    u16* __restrict__ oh, u16* __restrict__ ol) {
  const int n = blockIdx.x;
  const int c = threadIdx.x;
  __shared__ float sr[KNB][3];
  __shared__ float sf[KNB][4];
  if (c < KNB) {
    const int j = knn[n * KNB + c];
    sr[c][0] = xyz[j * 3 + 0] - xyz[n * 3 + 0];
    sr[c][1] = xyz[j * 3 + 1] - xyz[n * 3 + 1];
    sr[c][2] = xyz[j * 3 + 2] - xyz[n * 3 + 2];
    float f0 = x[j * 4 + 0] - x[n * 4 + 0];
    float f1 = x[j * 4 + 1] - x[n * 4 + 1];
    float f2 = x[j * 4 + 2] - x[n * 4 + 2];
    float f3 = x[j * 4 + 3] - x[n * 4 + 3];
    sf[c][0] = f0 * f0; sf[c][1] = f1 * f1;
    sf[c][2] = f2 * f2; sf[c][3] = f3 * f3;
  }
  __syncthreads();
  const float m0 = sm[c], m1 = sm[CH + c], m2 = sm[2 * CH + c];
  const float m4 = sm[4 * CH + c], m5 = sm[5 * CH + c], m6 = sm[6 * CH + c];
  const float m8 = sm[8 * CH + c], m9 = sm[9 * CH + c], m10 = sm[10 * CH + c];
  float c0 = sc[c];          c0 *= c0;
  float c1 = sc[CH + c];     c1 *= c1;
  float c2 = sc[2 * CH + c]; c2 *= c2;
  float h2 = sh[c];          h2 *= h2;
  float e = 0.0f;
#pragma unroll
  for (int k = 0; k < KNB; k++) {
    const float r0 = sr[k][0], r1 = sr[k][1], r2 = sr[k][2];
    const float d0 = fmaf(r2, m2, fmaf(r1, m1, r0 * m0));
    const float d1 = fmaf(r2, m6, fmaf(r1, m5, r0 * m4));
    const float d2 = fmaf(r2, m10, fmaf(r1, m9, r0 * m8));
    e = fmaf(d0, d0, e);
    e = fmaf(d1, d1, e);
    e = fmaf(d2, d2, e);
    e = fmaf(sf[k][0], c0, e);
    e = fmaf(sf[k][1], c1, e);
    e = fmaf(sf[k][2], c2, e);
    e = fmaf(sf[k][3], h2, e);
  }
  const float v = sqrtf(e * (1.0f / KNB)) * bnscale(g0[c]) + b0[c];
  u16 hi, lo; bf16split(v, hi, lo);
  const size_t idx = (size_t)n * CH + c;
  oh[idx] = hi; ol[idx] = lo;
}

// ---------------- LFP gather + PE + max + BN + residual (h as hi/lo) ----------------
// 256 thr = 8 points, 32 lanes/point, 4 ch/thread, float4 gathers
__global__ __launch_bounds__(256) void lfp_kernel(
    const float* __restrict__ xp, const int* __restrict__ knn,
    const float* __restrict__ xyz, const float* __restrict__ coor,
    const float* __restrict__ scale, const float* __restrict__ g,
    const float* __restrict__ b, u16* __restrict__ hh, u16* __restrict__ hl) {
  const int t = threadIdx.x;
  const int bid = blockIdx.x;
  __shared__ int si[8][KNB];
  __shared__ float sr[8][KNB][3];
  if (t < 128) {
    const int pp = t >> 4, kk = t & 15;
    const int n = bid * 8 + pp;
    const int j = knn[n * KNB + kk];
    si[pp][kk] = j;
    sr[pp][kk][0] = xyz[j * 3 + 0] - xyz[n * 3 + 0];
    sr[pp][kk][1] = xyz[j * 3 + 1] - xyz[n * 3 + 1];
    sr[pp][kk][2] = xyz[j * 3 + 2] - xyz[n * 3 + 2];
  }
  __syncthreads();
  const int p = t >> 5, d = t & 31;
  const int n = bid * 8 + p;
  const float c0 = coor[d], c1 = coor[32 + d], c2 = coor[64 + d];
  float s2 = scale[d]; s2 *= s2;
  float a0 = -3.0e38f, a1 = -3.0e38f, a2 = -3.0e38f, a3 = -3.0e38f;
#pragma unroll
  for (int k = 0; k < KNB; k++) {
    const int j = si[p][k];
    const float pe = fmaf(sr[p][k][2], c2, fmaf(sr[p][k][1], c1, sr[p][k][0] * c0)) * s2;
    const float4 v = *(const float4*)(xp + (size_t)j * CH + d * 4);
    a0 = fmaxf(a0, v.x + pe);
    a1 = fmaxf(a1, v.y + pe);
    a2 = fmaxf(a2, v.z + pe);
    a3 = fmaxf(a3, v.w + pe);
  }
  const size_t off = (size_t)n * CH + d * 4;
  const float4 gg = *(const float4*)(g + d * 4);
  const float4 bb = *(const float4*)(b + d * 4);
  union { u16 a[4]; uint2 v; } oh, olo, ih, il;
  ih.v = *(const uint2*)(hh + off);
  il.v = *(const uint2*)(hl + off);
  float nv[4];
  nv[0] = bf2f(ih.a[0]) + bf2f(il.a[0]) + a0 * bnscale(gg.x) + bb.x;
  nv[1] = bf2f(ih.a[1]) + bf2f(il.a[1]) + a1 * bnscale(gg.y) + bb.y;
  nv[2] = bf2f(ih.a[2]) + bf2f(il.a[2]) + a2 * bnscale(gg.z) + bb.z;
  nv[3] = bf2f(ih.a[3]) + bf2f(il.a[3]) + a3 * bnscale(gg.w) + bb.w;
#pragma unroll
  for (int q = 0; q < 4; q++) {
    u16 hi, lo; bf16split(nv[q], hi, lo);
    oh.a[q] = hi; olo.a[q] = lo;
  }
  *(uint2*)(hh + off) = oh.v;
  *(uint2*)(hl + off) = olo.v;
}

// ---------------- weight prep: transpose + bf16 hi/lo + swizzle ----------------
// dst (u16): nw1@0 [256][128], nw2@32768 [128][256], mw1[j]@65536+j*65536 [512][128],
// mw2[j]@262144+j*65536 [128][512], lproj[i]@458752+i*16384 [128][128], post@524288 [256][128]
// k128-read weights (nw1,mw1,lproj,post): 128-swizzle; w2 weights (nw2,mw2): 32-swizzle
__global__ __launch_bounds__(256) void prep_weights(
    const float* __restrict__ nw1, const float* __restrict__ nw2,
    const float* __restrict__ mw1, const float* __restrict__ mw2,
    const float* __restrict__ lproj, const float* __restrict__ pw,
    const float* __restrict__ pg, u16* __restrict__ th, u16* __restrict__ tl) {
  const int idx = blockIdx.x * 256 + threadIdx.x;
  const float* src;
  int local, Kd, Nd, dst, swz32;
  float scale = 1.0f;
  if (idx < 32768)        { src = nw1; local = idx;          Kd = 128; Nd = 256; dst = 0; swz32 = 0; }
  else if (idx < 65536)   { src = nw2; local = idx - 32768;  Kd = 256; Nd = 128; dst = 32768; swz32 = 1; }
  else if (idx < 262144)  { int j = (idx - 65536) >> 16;  local = (idx - 65536) & 65535;
                            src = mw1 + j * 65536; Kd = 128; Nd = 512; dst = 65536 + j * 65536; swz32 = 0; }
  else if (idx < 458752)  { int j = (idx - 262144) >> 16; local = (idx - 262144) & 65535;
                            src = mw2 + j * 65536; Kd = 512; Nd = 128; dst = 262144 + j * 65536; swz32 = 1; }
  else if (idx < 524288)  { int i = (idx - 458752) >> 14; local = (idx - 458752) & 16383;
                            src = lproj + i * 16384; Kd = 128; Nd = 128; dst = 458752 + i * 16384; swz32 = 0; }
  else if (idx < 557056)  { local = idx - 524288; src = pw; Kd = 128; Nd = 256; dst = 524288; swz32 = 0;
                            scale = bnscale(pg[local >> 8]); }
  else return;
  const int k = local / Nd, n = local % Nd;
  const float v = src[local] * scale;
  u16 hi, lo; bf16split(v, hi, lo);
  int ks;
  if (swz32) ks = (k & ~31) | ((k & 31) ^ ((n & 3) << 3));
  else       ks = (k & ~127) | ((k & 127) ^ ((n & 7) << 3));
  const int o = dst + n * Kd + ks;
  th[o] = hi; tl[o] = lo;
}

// folded post bias: fb[n] = sum_k pb[k] * pw[k][n]
__global__ __launch_bounds__(256) void fold_pb(const float* __restrict__ pw,
                                               const float* __restrict__ pb,
                                               float* __restrict__ fb) {
  const int t = threadIdx.x;
  float a = 0.0f;
  for (int k = 0; k < 128; k++) a = fmaf(pb[k], pw[k * 256 + t], a);
  fb[t] = a;
}

// ---------------- single-stall K=128 GEMM ----------------
// out = epi(A[M x 128] @ W[128 x 128colblk]); A hi/lo in regs (3-MFMA split),
// W staged once (pre-128-swizzled). BM=64, 4 waves 2x2. ONE barrier per block.
// EPI: 0 -> f32 store (xp); 1 -> gelu(v + bias) -> u16 hi (act); 2 -> v + bias -> f32 (out)
template <int EPI>
__global__ __launch_bounds__(256, 2) void k128(
    const u16* __restrict__ Ahi, const u16* __restrict__ Alo,
    const u16* __restrict__ Wh_g, const u16* __restrict__ Wl_g,
    const float* __restrict__ p0, float* __restrict__ outf,
    u16* __restrict__ outu, int ostride) {
  __shared__ __align__(16) u16 Wh_s[128 * 128];
  __shared__ __align__(16) u16 Wl_s[128 * 128];
  const int t = threadIdx.x, lane = t & 63, w = t >> 6;
  const int row0 = blockIdx.x * 64;
  const int col0 = blockIdx.y * 128;
  const int wm0 = (w >> 1) * 32, wn0 = (w & 1) * 64;
  const int lc = lane & 15, lq = lane >> 4;
  const int lq4 = lq * 4, lq8 = lq * 8;

  // A fragments first (longest latency, straight to regs)
  bf16x8 ah[2][4], al[2][4];
#pragma unroll
  for (int mf = 0; mf < 2; mf++)
#pragma unroll
    for (int ks = 0; ks < 4; ks++) {
      const size_t ao = (size_t)(row0 + wm0 + mf * 16 + lc) * 128 + ks * 32 + lq8;
      ah[mf][ks] = *(const bf16x8*)(Ahi + ao);
      al[mf][ks] = *(const bf16x8*)(Alo + ao);
    }
  stage128(Wh_s, Wh_g + (size_t)blockIdx.y * 16384, t);
  stage128(Wl_s, Wl_g + (size_t)blockIdx.y * 16384, t);

  const f32x4 zz = {0.0f, 0.0f, 0.0f, 0.0f};
  f32x4 acc[2][4];
#pragma unroll
  for (int mf = 0; mf < 2; mf++)
#pragma unroll
    for (int nf = 0; nf < 4; nf++) acc[mf][nf] = zz;

  __syncthreads();
#pragma unroll
  for (int ks = 0; ks < 4; ks++) {
    const int chunk = ks * 4 + lq;
    bf16x8 bh[4], bl[4];
#pragma unroll
    for (int nf = 0; nf < 4; nf++) {
      const int nr = wn0 + nf * 16 + lc;
      bh[nf] = ldw(Wh_s, nr, chunk);
      bl[nf] = ldw(Wl_s, nr, chunk);
    }
#pragma unroll
    for (int mf = 0; mf < 2; mf++)
#pragma unroll
      for (int nf = 0; nf < 4; nf++) {
        acc[mf][nf] = __builtin_amdgcn_mfma_f32_16x16x32_bf16(ah[mf][ks], bh[nf], acc[mf][nf], 0, 0, 0);
        acc[mf][nf] = __builtin_amdgcn_mfma_f32_16x16x32_bf16(ah[mf][ks], bl[nf], acc[mf][nf], 0, 0, 0);
        acc[mf][nf] = __builtin_amdgcn_mfma_f32_16x16x32_bf16(al[mf][ks], bh[nf], acc[mf][nf], 0, 0, 0);
      }
  }

  float bv[4];
#pragma unroll
  for (int nf = 0; nf < 4; nf++)
    bv[nf] = (EPI == 0) ? 0.0f : p0[col0 + wn0 + nf * 16 + lc];
#pragma unroll
  for (int mf = 0; mf < 2; mf++)
#pragma unroll
    for (int q = 0; q < 4; q++) {
      const int r = row0 + wm0 + mf * 16 + lq4 + q;
#pragma unroll
      for (int nf = 0; nf < 4; nf++) {
        const int col = col0 + wn0 + nf * 16 + lc;
        const size_t off = (size_t)r * ostride + col;
        const float v = acc[mf][nf][q] + bv[nf];
        if (EPI == 0)      outf[off] = v;
        else if (EPI == 1) outu[off] = f2bf(gelu_f(v));
        else               outf[off] = v;
      }
    }
}

// ---------------- double-buffered 2-phase w2 GEMM ----------------
// h' = [hi/lo(h) +] BN(A[M x K] @ W2[K x 128]); A bf16-hi linear (2-MFMA split),
// W2 pre-32-swizzled [128][K]. BM=64, BK=32, 4 waves 2x2, LDS 40 KB -> 4 blocks/CU.
template <int K, bool RES>
__global__ __launch_bounds__(256, 3) void gemm_w2(
    const u16* __restrict__ A, const u16* __restrict__ Bth,
    const u16* __restrict__ Btl, const float* __restrict__ g,
    const float* __restrict__ bb, u16* __restrict__ hh, u16* __restrict__ hl) {
  __shared__ __align__(16) u16 As[2][64 * 32];
  __shared__ __align__(16) u16 Bh[2][128 * 32];
  __shared__ __align__(16) u16 Bl[2][128 * 32];
  const int t = threadIdx.x, lane = t & 63, w = t >> 6;
  const int row0 = blockIdx.x * 64;
  const int wm0 = (w >> 1) * 32, wn0 = (w & 1) * 64;
  const int lc = lane & 15, lq = lane >> 4;
  const int lq4 = lq * 4, lq8 = lq * 8;

  const f32x4 zz = {0.0f, 0.0f, 0.0f, 0.0f};
  f32x4 acc[2][4];
#pragma unroll
  for (int mf = 0; mf < 2; mf++)
#pragma unroll
    for (int nf = 0; nf < 4; nf++) acc[mf][nf] = zz;

  stage_rows<64>(As[0], A, K, row0, 0, t);
  stage_rows<128>(Bh[0], Bth, K, 0, 0, t);
  stage_rows<128>(Bl[0], Btl, K, 0, 0, t);
  __syncthreads();

  constexpr int NT = K / 32;
#pragma unroll 1
  for (int tt = 0; tt < NT; tt++) {
    const int cur = tt & 1;
    if (tt + 1 < NT) {  // prefetch next K-slab into other buffer (flies under MFMA)
      const int kb = (tt + 1) * 32;
      stage_rows<64>(As[cur ^ 1], A, K, row0, kb, t);
      stage_rows<128>(Bh[cur ^ 1], Bth, K, 0, kb, t);
      stage_rows<128>(Bl[cur ^ 1], Btl, K, 0, kb, t);
    }
    bf16x8 af[2];
#pragma unroll
    for (int mf = 0; mf < 2; mf++)
      af[mf] = *(const bf16x8*)(As[cur] + (wm0 + mf * 16 + lc) * 32 + lq8);
    bf16x8 bh4[4], bl4[4];
#pragma unroll
    for (int nf = 0; nf < 4; nf++) {
      const int nr = wn0 + nf * 16 + lc;
      const int boff = nr * 32 + ((lq ^ (nr & 3)) << 3);
      bh4[nf] = *(const bf16x8*)(Bh[cur] + boff);
      bl4[nf] = *(const bf16x8*)(Bl[cur] + boff);
    }
#pragma unroll
    for (int mf = 0; mf < 2; mf++)
#pragma unroll
      for (int nf = 0; nf < 4; nf++) {
        acc[mf][nf] = __builtin_amdgcn_mfma_f32_16x16x32_bf16(af[mf], bh4[nf], acc[mf][nf], 0, 0, 0);
        acc[mf][nf] = __builtin_amdgcn_mfma_f32_16x16x32_bf16(af[mf], bl4[nf], acc[mf][nf], 0, 0, 0);
      }
    __syncthreads();  // drains prefetch (vmcnt0) + guards buffer reuse
  }

  float S0[4], S1[4];
#pragma unroll
  for (int nf = 0; nf < 4; nf++) {
    const int col = wn0 + nf * 16 + lc;
    S0[nf] = bnscale(g[col]);
    S1[nf] = bb[col];
  }
#pragma unroll
  for (int mf = 0; mf < 2; mf++)
#pragma unroll
    for (int q = 0; q < 4; q++) {
      const int r = row0 + wm0 + mf * 16 + lq4 + q;
#pragma unroll
      for (int nf = 0; nf < 4; nf++) {
        const int col = wn0 + nf * 16 + lc;
        const size_t off = (size_t)r * CH + col;
        float v = acc[mf][nf][q] * S0[nf] + S1[nf];
        if (RES) v += bf2f(hh[off]) + bf2f(hl[off]);
        u16 hi, lo; bf16split(v, hi, lo);
        hh[off] = hi; hl[off] = lo;
      }
    }
}

extern "C" void kernel_launch(void* const* d_in, const int* in_sizes, int n_in,
                              void* d_out, int out_size, void* d_ws, size_t ws_size,
                              hipStream_t stream) {
  const float* x    = (const float*)d_in[0];
  const float* xyz  = (const float*)d_in[1];
  const int*   knn  = (const int*)d_in[2];
  const float* sm   = (const float*)d_in[3];
  const float* scc  = (const float*)d_in[4];
  const float* shh  = (const float*)d_in[5];
  const float* bn0g = (const float*)d_in[6];
  const float* bn0b = (const float*)d_in[7];
  const float* nw1  = (const float*)d_in[8];
  const float* nb1  = (const float*)d_in[9];
  const float* nw2  = (const float*)d_in[10];
  const float* nbng = (const float*)d_in[11];
  const float* nbnb = (const float*)d_in[12];
  const float* lproj  = (const float*)d_in[13];
  const float* lcoor  = (const float*)d_in[14];
  const float* lscale = (const float*)d_in[15];
  const float* lbng   = (const float*)d_in[16];
  const float* lbnb   = (const float*)d_in[17];
  const float* mw1  = (const float*)d_in[18];
  const float* mb1  = (const float*)d_in[19];
  const float* mw2  = (const float*)d_in[20];
  const float* mbng = (const float*)d_in[21];
  const float* mbnb = (const float*)d_in[22];
  const float* pg   = (const float*)d_in[23];
  const float* pb   = (const float*)d_in[24];
  const float* pw   = (const float*)d_in[25];
  float* out = (float*)d_out;

  // workspace (bytes): h hi/lo, act/xp union, weights, fb
  char* ws = (char*)d_ws;
  u16*   h_hi = (u16*)(ws + 0);              // 10,240,000
  u16*   h_lo = (u16*)(ws + 10240000);       // 10,240,000
  u16*   act  = (u16*)(ws + 20480000);       // 40,960,000 (40000x512 bf16-hi)
  float* xp   = (float*)(ws + 20480000);     // 20,480,000 (aliases act; never co-live)
  u16*   Wh   = (u16*)(ws + 61440000);       // 1,114,112
  u16*   Wl   = (u16*)(ws + 62554112);       // 1,114,112
  float* fb   = (float*)(ws + 63668224);     // 1,024

  const u16* nw1t   = Wh + 0;
  const u16* nw2t   = Wh + 32768;
  const u16* mw1t   = Wh + 65536;
  const u16* mw2t   = Wh + 262144;
  const u16* lprojt = Wh + 458752;
  const u16* postt  = Wh + 524288;
  const u16* nw1tl   = Wl + 0;
  const u16* nw2tl   = Wl + 32768;
  const u16* mw1tl   = Wl + 65536;
  const u16* mw2tl   = Wl + 262144;
  const u16* lprojtl = Wl + 458752;
  const u16* posttl  = Wl + 524288;

  prep_weights<<<2176, 256, 0, stream>>>(nw1, nw2, mw1, mw2, lproj, pw, pg, Wh, Wl);
  fold_pb<<<1, 256, 0, stream>>>(pw, pb, fb);

  spse_kernel<<<NPTS, 128, 0, stream>>>(x, xyz, knn, sm, scc, shh, bn0g, bn0b, h_hi, h_lo);

  // nbr_proj: act = gelu(nbr@w1+b1); h = BN(act@w2)
  k128<1><<<dim3(625, 2), 256, 0, stream>>>(h_hi, h_lo, nw1t, nw1tl, nb1, nullptr, act, 256);
  gemm_w2<256, false><<<625, 256, 0, stream>>>(act, nw2t, nw2tl, nbng, nbnb, h_hi, h_lo);

  // mlp 0 (residual)
  k128<1><<<dim3(625, 4), 256, 0, stream>>>(h_hi, h_lo, mw1t, mw1tl, mb1, nullptr, act, 512);
  gemm_w2<512, true><<<625, 256, 0, stream>>>(act, mw2t, mw2tl, mbng, mbnb, h_hi, h_lo);

  for (int i = 0; i < 4; i++) {
    k128<0><<<dim3(625, 1), 256, 0, stream>>>(h_hi, h_lo, lprojt + i * 16384,
                                              lprojtl + i * 16384, nullptr, xp, nullptr, 128);
    lfp_kernel<<<5000, 256, 0, stream>>>(xp, knn, xyz, lcoor + i * 96, lscale + i * 32,
                                         lbng + i * 128, lbnb + i * 128, h_hi, h_lo);
    if (i & 1) {
      const int j = i / 2 + 1;
      k128<1><<<dim3(625, 4), 256, 0, stream>>>(h_hi, h_lo, mw1t + j * 65536,
                                                mw1tl + j * 65536, mb1 + j * 512,
                                                nullptr, act, 512);
      gemm_w2<512, true><<<625, 256, 0, stream>>>(act, mw2t + j * 65536, mw2tl + j * 65536,
                                                  mbng + j * 128, mbnb + j * 128, h_hi, h_lo);
    }
  }

  // postproj (BN folded into weights; rank-1 bias)
  k128<2><<<dim3(625, 2), 256, 0, stream>>>(h_hi, h_lo, postt, posttl, fb, out, nullptr, 256);
}

// Round 5
// 529.178 us; speedup vs baseline: 1.1924x; 1.0399x over previous
//
#include <hip/hip_runtime.h>
#include <hip/hip_bf16.h>
#include <math.h>

#define NPTS 40000
#define KNB 16
#define CH 128

typedef unsigned short u16;
typedef __attribute__((ext_vector_type(8))) short bf16x8;
typedef __attribute__((ext_vector_type(4))) float f32x4;

__device__ __forceinline__ float gelu_f(float v) {
  // 0.5*v*(1+tanh(u)) == v / (1 + exp2(-2*log2(e)*u)) ; u = 0.79788456*(v+0.044715 v^3)
  const float u = 0.7978845608028654f * (v + 0.044715f * v * v * v);
  const float t = __builtin_amdgcn_exp2f(-2.8853900817779268f * u);
  return v * __builtin_amdgcn_rcpf(1.0f + t);
}

__device__ __forceinline__ float bnscale(float g) {
  return g * rsqrtf(1.0f + 1e-5f);
}

__device__ __forceinline__ u16 f2bf(float x) {
  union { __hip_bfloat16 b; u16 u; } cv;
  cv.b = __float2bfloat16(x);
  return cv.u;
}

__device__ __forceinline__ float bf2f(u16 u) {
  union { float f; unsigned int i; } cv;
  cv.i = ((unsigned int)u) << 16;
  return cv.f;
}

__device__ __forceinline__ void bf16split(float x, u16& hi, u16& lo) {
  hi = f2bf(x);
  lo = f2bf(x - bf2f(hi));
}

// async global->LDS: 16B/lane, wave-uniform LDS base + lane*16
__device__ __forceinline__ void gl2lds(const u16* gp, u16* lp) {
  __builtin_amdgcn_global_load_lds(
      (const __attribute__((address_space(1))) void*)gp,
      (__attribute__((address_space(3))) void*)lp, 16, 0, 0);
}

// ---------------- knn_spse_4 + BN0 -> bf16 hi/lo ----------------
__global__ __launch_bounds__(128) void spse_kernel(
    const float* __restrict__ x, const float* __restrict__ xyz,
    const int* __restrict__ knn, const float* __restrict__ sm,
    const float* __restrict__ sc, const float* __restrict__ sh,
    const float* __restrict__ g0, const float* __restrict__ b0,
    u16* __restrict__ oh, u16* __restrict__ ol) {
  const int n = blockIdx.x;
  const int c = threadIdx.x;
  __shared__ float sr[KNB][3];
  __shared__ float sf[KNB][4];
  if (c < KNB) {
    const int j = knn[n * KNB + c];
    sr[c][0] = xyz[j * 3 + 0] - xyz[n * 3 + 0];
    sr[c][1] = xyz[j * 3 + 1] - xyz[n * 3 + 1];
    sr[c][2] = xyz[j * 3 + 2] - xyz[n * 3 + 2];
    float f0 = x[j * 4 + 0] - x[n * 4 + 0];
    float f1 = x[j * 4 + 1] - x[n * 4 + 1];
    float f2 = x[j * 4 + 2] - x[n * 4 + 2];
    float f3 = x[j * 4 + 3] - x[n * 4 + 3];
    sf[c][0] = f0 * f0; sf[c][1] = f1 * f1;
    sf[c][2] = f2 * f2; sf[c][3] = f3 * f3;
  }
  __syncthreads();
  const float m0 = sm[c], m1 = sm[CH + c], m2 = sm[2 * CH + c];
  const float m4 = sm[4 * CH + c], m5 = sm[5 * CH + c], m6 = sm[6 * CH + c];
  const float m8 = sm[8 * CH + c], m9 = sm[9 * CH + c], m10 = sm[10 * CH + c];
  float c0 = sc[c];          c0 *= c0;
  float c1 = sc[CH + c];     c1 *= c1;
  float c2 = sc[2 * CH + c]; c2 *= c2;
  float h2 = sh[c];          h2 *= h2;
  float e = 0.0f;
#pragma unroll
  for (int k = 0; k < KNB; k++) {
    const float r0 = sr[k][0], r1 = sr[k][1], r2 = sr[k][2];
    const float d0 = fmaf(r2, m2, fmaf(r1, m1, r0 * m0));
    const float d1 = fmaf(r2, m6, fmaf(r1, m5, r0 * m4));
    const float d2 = fmaf(r2, m10, fmaf(r1, m9, r0 * m8));
    e = fmaf(d0, d0, e);
    e = fmaf(d1, d1, e);
    e = fmaf(d2, d2, e);
    e = fmaf(sf[k][0], c0, e);
    e = fmaf(sf[k][1], c1, e);
    e = fmaf(sf[k][2], c2, e);
    e = fmaf(sf[k][3], h2, e);
  }
  const float v = sqrtf(e * (1.0f / KNB)) * bnscale(g0[c]) + b0[c];
  u16 hi, lo; bf16split(v, hi, lo);
  const size_t idx = (size_t)n * CH + c;
  oh[idx] = hi; ol[idx] = lo;
}

// ---------------- LFP gather + PE + max + BN + residual (h as hi/lo) ----------------
// 256 thr = 8 points, 32 lanes/point, 4 ch/thread, 8B bf16x4 gathers
__global__ __launch_bounds__(256) void lfp_kernel(
    const u16* __restrict__ xp, const int* __restrict__ knn,
    const float* __restrict__ xyz, const float* __restrict__ coor,
    const float* __restrict__ scale, const float* __restrict__ g,
    const float* __restrict__ b, u16* __restrict__ hh, u16* __restrict__ hl) {
  const int t = threadIdx.x;
  const int bid = blockIdx.x;
  __shared__ int si[8][KNB];
  __shared__ float sr[8][KNB][3];
  if (t < 128) {
    const int pp = t >> 4, kk = t & 15;
    const int n = bid * 8 + pp;
    const int j = knn[n * KNB + kk];
    si[pp][kk] = j;
    sr[pp][kk][0] = xyz[j * 3 + 0] - xyz[n * 3 + 0];
    sr[pp][kk][1] = xyz[j * 3 + 1] - xyz[n * 3 + 1];
    sr[pp][kk][2] = xyz[j * 3 + 2] - xyz[n * 3 + 2];
  }
  __syncthreads();
  const int p = t >> 5, d = t & 31;
  const int n = bid * 8 + p;
  const float c0 = coor[d], c1 = coor[32 + d], c2 = coor[64 + d];
  float s2 = scale[d]; s2 *= s2;
  float a0 = -3.0e38f, a1 = -3.0e38f, a2 = -3.0e38f, a3 = -3.0e38f;
#pragma unroll
  for (int k = 0; k < KNB; k++) {
    const int j = si[p][k];
    const float pe = fmaf(sr[p][k][2], c2, fmaf(sr[p][k][1], c1, sr[p][k][0] * c0)) * s2;
    const uint2 v = *(const uint2*)(xp + (size_t)j * CH + d * 4);
    a0 = fmaxf(a0, bf2f((u16)(v.x & 0xffff)) + pe);
    a1 = fmaxf(a1, bf2f((u16)(v.x >> 16)) + pe);
    a2 = fmaxf(a2, bf2f((u16)(v.y & 0xffff)) + pe);
    a3 = fmaxf(a3, bf2f((u16)(v.y >> 16)) + pe);
  }
  const size_t off = (size_t)n * CH + d * 4;
  const float4 gg = *(const float4*)(g + d * 4);
  const float4 bb = *(const float4*)(b + d * 4);
  union { u16 a[4]; uint2 v; } oh, olo, ih, il;
  ih.v = *(const uint2*)(hh + off);
  il.v = *(const uint2*)(hl + off);
  float nv[4];
  nv[0] = bf2f(ih.a[0]) + bf2f(il.a[0]) + a0 * bnscale(gg.x) + bb.x;
  nv[1] = bf2f(ih.a[1]) + bf2f(il.a[1]) + a1 * bnscale(gg.y) + bb.y;
  nv[2] = bf2f(ih.a[2]) + bf2f(il.a[2]) + a2 * bnscale(gg.z) + bb.z;
  nv[3] = bf2f(ih.a[3]) + bf2f(il.a[3]) + a3 * bnscale(gg.w) + bb.w;
#pragma unroll
  for (int q = 0; q < 4; q++) {
    u16 hi, lo; bf16split(nv[q], hi, lo);
    oh.a[q] = hi; olo.a[q] = lo;
  }
  *(uint2*)(hh + off) = oh.v;
  *(uint2*)(hl + off) = olo.v;
}

// ---------------- weight prep: transpose + bf16 hi/lo (+64-window swizzle for w2) ----
// dst (u16): nw1@0 [256][128], nw2@32768 [128][256]swz, mw1[j]@65536+j*65536 [512][128],
// mw2[j]@262144+j*65536 [128][512]swz, lproj[i]@458752+i*16384 [128][128], post@524288 [256][128]
__global__ __launch_bounds__(256) void prep_weights(
    const float* __restrict__ nw1, const float* __restrict__ nw2,
    const float* __restrict__ mw1, const float* __restrict__ mw2,
    const float* __restrict__ lproj, const float* __restrict__ pw,
    const float* __restrict__ pg, u16* __restrict__ th, u16* __restrict__ tl) {
  const int idx = blockIdx.x * 256 + threadIdx.x;
  const float* src;
  int local, Kd, Nd, dst, swz;
  float scale = 1.0f;
  if (idx < 32768)        { src = nw1; local = idx;          Kd = 128; Nd = 256; dst = 0; swz = 0; }
  else if (idx < 65536)   { src = nw2; local = idx - 32768;  Kd = 256; Nd = 128; dst = 32768; swz = 1; }
  else if (idx < 262144)  { int j = (idx - 65536) >> 16;  local = (idx - 65536) & 65535;
                            src = mw1 + j * 65536; Kd = 128; Nd = 512; dst = 65536 + j * 65536; swz = 0; }
  else if (idx < 458752)  { int j = (idx - 262144) >> 16; local = (idx - 262144) & 65535;
                            src = mw2 + j * 65536; Kd = 512; Nd = 128; dst = 262144 + j * 65536; swz = 1; }
  else if (idx < 524288)  { int i = (idx - 458752) >> 14; local = (idx - 458752) & 16383;
                            src = lproj + i * 16384; Kd = 128; Nd = 128; dst = 458752 + i * 16384; swz = 0; }
  else if (idx < 557056)  { local = idx - 524288; src = pw; Kd = 128; Nd = 256; dst = 524288; swz = 0;
                            scale = bnscale(pg[local >> 8]); }
  else return;
  const int k = local / Nd, n = local % Nd;
  const float v = src[local] * scale;
  u16 hi, lo; bf16split(v, hi, lo);
  const int ks = swz ? ((k & ~63) | ((k & 63) ^ ((n & 7) << 3))) : k;
  const int o = dst + n * Kd + ks;
  th[o] = hi; tl[o] = lo;
}

// folded post bias: fb[n] = sum_k pb[k] * pw[k][n]
__global__ __launch_bounds__(256) void fold_pb(const float* __restrict__ pw,
                                               const float* __restrict__ pb,
                                               float* __restrict__ fb) {
  const int t = threadIdx.x;
  float a = 0.0f;
  for (int k = 0; k < 128; k++) a = fmaf(pb[k], pw[k * 256 + t], a);
  fb[t] = a;
}

// ---------------- barrier-free streaming K=128 GEMM, W in registers ----------------
// out = epi(A[M x 128] @ W[128colblk x 128]^T); W frags (hi+lo) reg-resident,
// A hi/lo direct global->reg (3-MFMA split). BM=64/tile, 4 waves 2x2, grid-stride M.
// EPI: 0 -> bf16 store (xp); 1 -> gelu(v+bias) -> u16 act; 2 -> v+bias -> f32 out
template <int EPI>
__global__ __launch_bounds__(256, 2) void k128_reg(
    const u16* __restrict__ Ahi, const u16* __restrict__ Alo,
    const u16* __restrict__ Wth, const u16* __restrict__ Wtl,
    const float* __restrict__ p0, u16* __restrict__ outu,
    float* __restrict__ outf, int ostride, int ntiles) {
  const int t = threadIdx.x, lane = t & 63, w = t >> 6;
  const int col0 = blockIdx.x * 128;
  const int wm0 = (w >> 1) * 32, wn0 = (w & 1) * 64;
  const int lc = lane & 15, lq = lane >> 4;
  const int lq8 = lq * 8, lq4 = lq * 4;

  // W fragments resident for this wave's 64-col slice: nf(4) x kchunk(4), hi+lo
  bf16x8 wh[4][4], wl[4][4];
  float bv[4];
#pragma unroll
  for (int nf = 0; nf < 4; nf++) {
    const int nr = col0 + wn0 + nf * 16 + lc;
    const u16* wr = Wth + (size_t)nr * 128;
    const u16* wr2 = Wtl + (size_t)nr * 128;
#pragma unroll
    for (int ks = 0; ks < 4; ks++) {
      wh[nf][ks] = *(const bf16x8*)(wr + ks * 32 + lq8);
      wl[nf][ks] = *(const bf16x8*)(wr2 + ks * 32 + lq8);
    }
    bv[nf] = (EPI == 0) ? 0.0f : p0[nr];
  }

  const f32x4 zz = {0.0f, 0.0f, 0.0f, 0.0f};
  for (int tile = blockIdx.y; tile < ntiles; tile += gridDim.y) {
    const int row0 = tile * 64;
    f32x4 acc[2][4];
#pragma unroll
    for (int mf = 0; mf < 2; mf++)
#pragma unroll
      for (int nf = 0; nf < 4; nf++) acc[mf][nf] = zz;
#pragma unroll
    for (int ks = 0; ks < 4; ks++) {
      bf16x8 ah[2], al[2];
#pragma unroll
      for (int mf = 0; mf < 2; mf++) {
        const size_t ao = (size_t)(row0 + wm0 + mf * 16 + lc) * 128 + ks * 32 + lq8;
        ah[mf] = *(const bf16x8*)(Ahi + ao);
        al[mf] = *(const bf16x8*)(Alo + ao);
      }
#pragma unroll
      for (int mf = 0; mf < 2; mf++)
#pragma unroll
        for (int nf = 0; nf < 4; nf++) {
          acc[mf][nf] = __builtin_amdgcn_mfma_f32_16x16x32_bf16(ah[mf], wh[nf][ks], acc[mf][nf], 0, 0, 0);
          acc[mf][nf] = __builtin_amdgcn_mfma_f32_16x16x32_bf16(ah[mf], wl[nf][ks], acc[mf][nf], 0, 0, 0);
          acc[mf][nf] = __builtin_amdgcn_mfma_f32_16x16x32_bf16(al[mf], wh[nf][ks], acc[mf][nf], 0, 0, 0);
        }
    }
#pragma unroll
    for (int mf = 0; mf < 2; mf++)
#pragma unroll
      for (int q = 0; q < 4; q++) {
        const int r = row0 + wm0 + mf * 16 + lq4 + q;
#pragma unroll
        for (int nf = 0; nf < 4; nf++) {
          const int col = col0 + wn0 + nf * 16 + lc;
          const size_t off = (size_t)r * ostride + col;
          const float v = acc[mf][nf][q];
          if (EPI == 0)      outu[off] = f2bf(v);
          else if (EPI == 1) outu[off] = f2bf(gelu_f(v + bv[nf]));
          else               outf[off] = v + bv[nf];
        }
      }
  }
}

// ---------------- w2 GEMM: h' = [h +] BN(act[M x K] @ W2[K x 128]) ----------------
// W2-hi col-half persistent in LDS (staged once, 64-window XOR swizzle);
// W2-lo frags direct from global (L2-hot); act frags direct global->reg.
// 512 thr = 8 waves: 4 x 64-row subtiles x 2 x 32-col groups; 256-row steps.
template <int K, bool RES>
__global__ __launch_bounds__(512, 4) void gemm_w2(
    const u16* __restrict__ A, const u16* __restrict__ Wth,
    const u16* __restrict__ Wtl, const float* __restrict__ g,
    const float* __restrict__ bb, u16* __restrict__ hh, u16* __restrict__ hl) {
  __shared__ __align__(16) u16 Ws[64 * K];
  const int t = threadIdx.x, lane = t & 63, w = t >> 6;
  const int ch = blockIdx.x;          // 64-col half of the 128 output cols
  const int row0 = blockIdx.y * 256;
  const int msub = w >> 1, cg = w & 1;
  const int lc = lane & 15, lq = lane >> 4;
  const int lq8 = lq * 8, lq4 = lq * 4;

  {  // stage W2-hi half (64 rows x K), contiguous
    const u16* src = Wth + (size_t)ch * 64 * K;
#pragma unroll
    for (int i = 0; i < 64 * K / 8; i += 512) {
      const int wc0 = i + w * 64;
      const int c = wc0 + lane;
      gl2lds(src + (size_t)c * 8, Ws + wc0 * 8);
    }
  }
  __syncthreads();

  const int wrow0 = msub * 64;
  const f32x4 zz = {0.0f, 0.0f, 0.0f, 0.0f};
  f32x4 acc[4][2];
#pragma unroll
  for (int mf = 0; mf < 4; mf++)
#pragma unroll
    for (int nf = 0; nf < 2; nf++) acc[mf][nf] = zz;

#pragma unroll 2
  for (int ks = 0; ks < K / 32; ks++) {
    const int e = ks * 32 + lq8;
    bf16x8 af[4];
#pragma unroll
    for (int mf = 0; mf < 4; mf++) {
      int rr = row0 + wrow0 + mf * 16 + lc;
      rr = rr < NPTS ? rr : NPTS - 1;
      af[mf] = *(const bf16x8*)(A + (size_t)rr * K + e);
    }
    bf16x8 whf[2], wlf[2];
#pragma unroll
    for (int nf = 0; nf < 2; nf++) {
      const int nr = cg * 32 + nf * 16 + lc;
      const int eo = (e & ~63) | ((e & 63) ^ ((nr & 7) << 3));
      whf[nf] = *(const bf16x8*)(Ws + nr * K + eo);
      wlf[nf] = *(const bf16x8*)(Wtl + (size_t)(ch * 64 + nr) * K + eo);
    }
#pragma unroll
    for (int mf = 0; mf < 4; mf++)
#pragma unroll
      for (int nf = 0; nf < 2; nf++) {
        acc[mf][nf] = __builtin_amdgcn_mfma_f32_16x16x32_bf16(af[mf], whf[nf], acc[mf][nf], 0, 0, 0);
        acc[mf][nf] = __builtin_amdgcn_mfma_f32_16x16x32_bf16(af[mf], wlf[nf], acc[mf][nf], 0, 0, 0);
      }
  }

  float S0[2], S1[2];
#pragma unroll
  for (int nf = 0; nf < 2; nf++) {
    const int col = ch * 64 + cg * 32 + nf * 16 + lc;
    S0[nf] = bnscale(g[col]);
    S1[nf] = bb[col];
  }
#pragma unroll
  for (int mf = 0; mf < 4; mf++)
#pragma unroll
    for (int q = 0; q < 4; q++) {
      const int r = row0 + wrow0 + mf * 16 + lq4 + q;
      if (r >= NPTS) continue;
#pragma unroll
      for (int nf = 0; nf < 2; nf++) {
        const int col = ch * 64 + cg * 32 + nf * 16 + lc;
        const size_t off = (size_t)r * CH + col;
        float v = acc[mf][nf][q] * S0[nf] + S1[nf];
        if (RES) v += bf2f(hh[off]) + bf2f(hl[off]);
        u16 hi, lo; bf16split(v, hi, lo);
        hh[off] = hi; hl[off] = lo;
      }
    }
}

extern "C" void kernel_launch(void* const* d_in, const int* in_sizes, int n_in,
                              void* d_out, int out_size, void* d_ws, size_t ws_size,
                              hipStream_t stream) {
  const float* x    = (const float*)d_in[0];
  const float* xyz  = (const float*)d_in[1];
  const int*   knn  = (const int*)d_in[2];
  const float* sm   = (const float*)d_in[3];
  const float* scc  = (const float*)d_in[4];
  const float* shh  = (const float*)d_in[5];
  const float* bn0g = (const float*)d_in[6];
  const float* bn0b = (const float*)d_in[7];
  const float* nw1  = (const float*)d_in[8];
  const float* nb1  = (const float*)d_in[9];
  const float* nw2  = (const float*)d_in[10];
  const float* nbng = (const float*)d_in[11];
  const float* nbnb = (const float*)d_in[12];
  const float* lproj  = (const float*)d_in[13];
  const float* lcoor  = (const float*)d_in[14];
  const float* lscale = (const float*)d_in[15];
  const float* lbng   = (const float*)d_in[16];
  const float* lbnb   = (const float*)d_in[17];
  const float* mw1  = (const float*)d_in[18];
  const float* mb1  = (const float*)d_in[19];
  const float* mw2  = (const float*)d_in[20];
  const float* mbng = (const float*)d_in[21];
  const float* mbnb = (const float*)d_in[22];
  const float* pg   = (const float*)d_in[23];
  const float* pb   = (const float*)d_in[24];
  const float* pw   = (const float*)d_in[25];
  float* out = (float*)d_out;

  // workspace (bytes)
  char* ws = (char*)d_ws;
  u16*   h_hi = (u16*)(ws + 0);              // 10,240,000
  u16*   h_lo = (u16*)(ws + 10240000);       // 10,240,000
  u16*   act  = (u16*)(ws + 20480000);       // 40,960,000 (40000x512 bf16-hi)
  u16*   xp   = (u16*)(ws + 20480000);       // 10,240,000 (aliases act; never co-live)
  u16*   Wh   = (u16*)(ws + 61440000);       // 1,114,112
  u16*   Wl   = (u16*)(ws + 62554112);       // 1,114,112
  float* fb   = (float*)(ws + 63668224);     // 1,024

  const u16* nw1t   = Wh + 0;
  const u16* nw2t   = Wh + 32768;
  const u16* mw1t   = Wh + 65536;
  const u16* mw2t   = Wh + 262144;
  const u16* lprojt = Wh + 458752;
  const u16* postt  = Wh + 524288;
  const u16* nw1tl   = Wl + 0;
  const u16* nw2tl   = Wl + 32768;
  const u16* mw1tl   = Wl + 65536;
  const u16* mw2tl   = Wl + 262144;
  const u16* lprojtl = Wl + 458752;
  const u16* posttl  = Wl + 524288;

  prep_weights<<<2176, 256, 0, stream>>>(nw1, nw2, mw1, mw2, lproj, pw, pg, Wh, Wl);
  fold_pb<<<1, 256, 0, stream>>>(pw, pb, fb);

  spse_kernel<<<NPTS, 128, 0, stream>>>(x, xyz, knn, sm, scc, shh, bn0g, bn0b, h_hi, h_lo);

  // nbr_proj: act = gelu(nbr@w1+b1); h = BN(act@w2)
  k128_reg<1><<<dim3(2, 256), 256, 0, stream>>>(h_hi, h_lo, nw1t, nw1tl, nb1,
                                                act, nullptr, 256, 625);
  gemm_w2<256, false><<<dim3(2, 157), 512, 0, stream>>>(act, nw2t, nw2tl, nbng, nbnb,
                                                        h_hi, h_lo);
  // mlp 0 (residual)
  k128_reg<1><<<dim3(4, 128), 256, 0, stream>>>(h_hi, h_lo, mw1t, mw1tl, mb1,
                                                act, nullptr, 512, 625);
  gemm_w2<512, true><<<dim3(2, 157), 512, 0, stream>>>(act, mw2t, mw2tl, mbng, mbnb,
                                                       h_hi, h_lo);

  for (int i = 0; i < 4; i++) {
    k128_reg<0><<<dim3(1, 512), 256, 0, stream>>>(h_hi, h_lo, lprojt + i * 16384,
                                                  lprojtl + i * 16384, nullptr,
                                                  xp, nullptr, 128, 625);
    lfp_kernel<<<5000, 256, 0, stream>>>(xp, knn, xyz, lcoor + i * 96, lscale + i * 32,
                                         lbng + i * 128, lbnb + i * 128, h_hi, h_lo);
    if (i & 1) {
      const int j = i / 2 + 1;
      k128_reg<1><<<dim3(4, 128), 256, 0, stream>>>(h_hi, h_lo, mw1t + j * 65536,
                                                    mw1tl + j * 65536, mb1 + j * 512,
                                                    act, nullptr, 512, 625);
      gemm_w2<512, true><<<dim3(2, 157), 512, 0, stream>>>(act, mw2t + j * 65536,
                                                           mw2tl + j * 65536,
                                                           mbng + j * 128, mbnb + j * 128,
                                                           h_hi, h_lo);
    }
  }

  // postproj (BN folded into weights; rank-1 bias)
  k128_reg<2><<<dim3(2, 256), 256, 0, stream>>>(h_hi, h_lo, postt, posttl, fb,
                                                nullptr, out, 256, 625);
}

// Round 6
// 497.185 us; speedup vs baseline: 1.2692x; 1.0643x over previous
//
#include <hip/hip_runtime.h>
#include <hip/hip_bf16.h>
#include <math.h>

#define NPTS 40000
#define KNB 16
#define CH 128

typedef unsigned short u16;
typedef __attribute__((ext_vector_type(8))) short bf16x8;
typedef __attribute__((ext_vector_type(4))) float f32x4;

__device__ __forceinline__ float gelu_f(float v) {
  const float u = 0.7978845608028654f * (v + 0.044715f * v * v * v);
  const float t = __builtin_amdgcn_exp2f(-2.8853900817779268f * u);
  return v * __builtin_amdgcn_rcpf(1.0f + t);
}

__device__ __forceinline__ float bnscale(float g) {
  return g * rsqrtf(1.0f + 1e-5f);
}

__device__ __forceinline__ u16 f2bf(float x) {
  union { __hip_bfloat16 b; u16 u; } cv;
  cv.b = __float2bfloat16(x);
  return cv.u;
}

__device__ __forceinline__ float bf2f(u16 u) {
  union { float f; unsigned int i; } cv;
  cv.i = ((unsigned int)u) << 16;
  return cv.f;
}

__device__ __forceinline__ void bf16split(float x, u16& hi, u16& lo) {
  hi = f2bf(x);
  lo = f2bf(x - bf2f(hi));
}

// async global->LDS: 16B/lane, wave-uniform LDS base + lane*16
__device__ __forceinline__ void gl2lds(const u16* gp, u16* lp) {
  __builtin_amdgcn_global_load_lds(
      (const __attribute__((address_space(1))) void*)gp,
      (__attribute__((address_space(3))) void*)lp, 16, 0, 0);
}

// ---------------- knn_spse_4 + BN0 -> bf16 hi/lo ----------------
__global__ __launch_bounds__(128) void spse_kernel(
    const float* __restrict__ x, const float* __restrict__ xyz,
    const int* __restrict__ knn, const float* __restrict__ sm,
    const float* __restrict__ sc, const float* __restrict__ sh,
    const float* __restrict__ g0, const float* __restrict__ b0,
    u16* __restrict__ oh, u16* __restrict__ ol) {
  const int n = blockIdx.x;
  const int c = threadIdx.x;
  __shared__ float sr[KNB][3];
  __shared__ float sf[KNB][4];
  if (c < KNB) {
    const int j = knn[n * KNB + c];
    sr[c][0] = xyz[j * 3 + 0] - xyz[n * 3 + 0];
    sr[c][1] = xyz[j * 3 + 1] - xyz[n * 3 + 1];
    sr[c][2] = xyz[j * 3 + 2] - xyz[n * 3 + 2];
    float f0 = x[j * 4 + 0] - x[n * 4 + 0];
    float f1 = x[j * 4 + 1] - x[n * 4 + 1];
    float f2 = x[j * 4 + 2] - x[n * 4 + 2];
    float f3 = x[j * 4 + 3] - x[n * 4 + 3];
    sf[c][0] = f0 * f0; sf[c][1] = f1 * f1;
    sf[c][2] = f2 * f2; sf[c][3] = f3 * f3;
  }
  __syncthreads();
  const float m0 = sm[c], m1 = sm[CH + c], m2 = sm[2 * CH + c];
  const float m4 = sm[4 * CH + c], m5 = sm[5 * CH + c], m6 = sm[6 * CH + c];
  const float m8 = sm[8 * CH + c], m9 = sm[9 * CH + c], m10 = sm[10 * CH + c];
  float c0 = sc[c];          c0 *= c0;
  float c1 = sc[CH + c];     c1 *= c1;
  float c2 = sc[2 * CH + c]; c2 *= c2;
  float h2 = sh[c];          h2 *= h2;
  float e = 0.0f;
#pragma unroll
  for (int k = 0; k < KNB; k++) {
    const float r0 = sr[k][0], r1 = sr[k][1], r2 = sr[k][2];
    const float d0 = fmaf(r2, m2, fmaf(r1, m1, r0 * m0));
    const float d1 = fmaf(r2, m6, fmaf(r1, m5, r0 * m4));
    const float d2 = fmaf(r2, m10, fmaf(r1, m9, r0 * m8));
    e = fmaf(d0, d0, e);
    e = fmaf(d1, d1, e);
    e = fmaf(d2, d2, e);
    e = fmaf(sf[k][0], c0, e);
    e = fmaf(sf[k][1], c1, e);
    e = fmaf(sf[k][2], c2, e);
    e = fmaf(sf[k][3], h2, e);
  }
  const float v = sqrtf(e * (1.0f / KNB)) * bnscale(g0[c]) + b0[c];
  u16 hi, lo; bf16split(v, hi, lo);
  const size_t idx = (size_t)n * CH + c;
  oh[idx] = hi; ol[idx] = lo;
}

// ---------------- LFP gather + PE + max + BN + residual (h as hi/lo) ----------------
// 256 thr = 16 points, 16 lanes/point, 8 ch/lane, 16B bf16x8 gathers
// (each (point,nbr) row gather = 16 lanes x 16B = full 256B row, perfectly coalesced)
__global__ __launch_bounds__(256) void lfp_kernel(
    const u16* __restrict__ xp, const int* __restrict__ knn,
    const float* __restrict__ xyz, const float* __restrict__ coor,
    const float* __restrict__ scale, const float* __restrict__ g,
    const float* __restrict__ b, u16* __restrict__ hh, u16* __restrict__ hl) {
  const int t = threadIdx.x;
  const int bid = blockIdx.x;
  __shared__ int si[16][KNB];
  __shared__ float sr[16][KNB][3];
  {
    const int pp = t >> 4, kk = t & 15;
    const int n = bid * 16 + pp;
    const int j = knn[n * KNB + kk];
    si[pp][kk] = j;
    sr[pp][kk][0] = xyz[j * 3 + 0] - xyz[n * 3 + 0];
    sr[pp][kk][1] = xyz[j * 3 + 1] - xyz[n * 3 + 1];
    sr[pp][kk][2] = xyz[j * 3 + 2] - xyz[n * 3 + 2];
  }
  __syncthreads();
  const int p = t >> 4, d8 = t & 15;   // channels c = d8*8 .. d8*8+7
  const int n = bid * 16 + p;
  const float c0a = coor[d8 * 2],     c1a = coor[32 + d8 * 2],     c2a = coor[64 + d8 * 2];
  const float c0b = coor[d8 * 2 + 1], c1b = coor[32 + d8 * 2 + 1], c2b = coor[64 + d8 * 2 + 1];
  float s2a = scale[d8 * 2];     s2a *= s2a;
  float s2b = scale[d8 * 2 + 1]; s2b *= s2b;
  float a[8];
#pragma unroll
  for (int e = 0; e < 8; e++) a[e] = -3.0e38f;
#pragma unroll
  for (int k = 0; k < KNB; k++) {
    const int j = si[p][k];
    const float r0 = sr[p][k][0], r1 = sr[p][k][1], r2 = sr[p][k][2];
    const float pea = fmaf(r2, c2a, fmaf(r1, c1a, r0 * c0a)) * s2a;
    const float peb = fmaf(r2, c2b, fmaf(r1, c1b, r0 * c0b)) * s2b;
    const bf16x8 v = *(const bf16x8*)(xp + (size_t)j * CH + d8 * 8);
#pragma unroll
    for (int e = 0; e < 4; e++) a[e] = fmaxf(a[e], bf2f((u16)v[e]) + pea);
#pragma unroll
    for (int e = 4; e < 8; e++) a[e] = fmaxf(a[e], bf2f((u16)v[e]) + peb);
  }
  const size_t off = (size_t)n * CH + d8 * 8;
  union { u16 a[8]; uint4 v; } ih, il, oh, ol;
  ih.v = *(const uint4*)(hh + off);
  il.v = *(const uint4*)(hl + off);
#pragma unroll
  for (int e = 0; e < 8; e++) {
    const int c = d8 * 8 + e;
    const float nv = bf2f(ih.a[e]) + bf2f(il.a[e]) + a[e] * bnscale(g[c]) + b[c];
    u16 hi, lo; bf16split(nv, hi, lo);
    oh.a[e] = hi; ol.a[e] = lo;
  }
  *(uint4*)(hh + off) = oh.v;
  *(uint4*)(hl + off) = ol.v;
}

// ---------------- weight prep: transpose + bf16 hi/lo (+64-window swizzle for w2) ----
__global__ __launch_bounds__(256) void prep_weights(
    const float* __restrict__ nw1, const float* __restrict__ nw2,
    const float* __restrict__ mw1, const float* __restrict__ mw2,
    const float* __restrict__ lproj, const float* __restrict__ pw,
    const float* __restrict__ pg, u16* __restrict__ th, u16* __restrict__ tl) {
  const int idx = blockIdx.x * 256 + threadIdx.x;
  const float* src;
  int local, Kd, Nd, dst, swz;
  float scale = 1.0f;
  if (idx < 32768)        { src = nw1; local = idx;          Kd = 128; Nd = 256; dst = 0; swz = 0; }
  else if (idx < 65536)   { src = nw2; local = idx - 32768;  Kd = 256; Nd = 128; dst = 32768; swz = 1; }
  else if (idx < 262144)  { int j = (idx - 65536) >> 16;  local = (idx - 65536) & 65535;
                            src = mw1 + j * 65536; Kd = 128; Nd = 512; dst = 65536 + j * 65536; swz = 0; }
  else if (idx < 458752)  { int j = (idx - 262144) >> 16; local = (idx - 262144) & 65535;
                            src = mw2 + j * 65536; Kd = 512; Nd = 128; dst = 262144 + j * 65536; swz = 1; }
  else if (idx < 524288)  { int i = (idx - 458752) >> 14; local = (idx - 458752) & 16383;
                            src = lproj + i * 16384; Kd = 128; Nd = 128; dst = 458752 + i * 16384; swz = 0; }
  else if (idx < 557056)  { local = idx - 524288; src = pw; Kd = 128; Nd = 256; dst = 524288; swz = 0;
                            scale = bnscale(pg[local >> 8]); }
  else return;
  const int k = local / Nd, n = local % Nd;
  const float v = src[local] * scale;
  u16 hi, lo; bf16split(v, hi, lo);
  const int ks = swz ? ((k & ~63) | ((k & 63) ^ ((n & 7) << 3))) : k;
  const int o = dst + n * Kd + ks;
  th[o] = hi; tl[o] = lo;
}

// folded post bias: fb[n] = sum_k pb[k] * pw[k][n]
__global__ __launch_bounds__(256) void fold_pb(const float* __restrict__ pw,
                                               const float* __restrict__ pb,
                                               float* __restrict__ fb) {
  const int t = threadIdx.x;
  float a = 0.0f;
  for (int k = 0; k < 128; k++) a = fmaf(pb[k], pw[k * 256 + t], a);
  fb[t] = a;
}

// ---------------- barrier-free streaming K=128 GEMM, W in registers ----------------
// grid: x = row-tile slots (fast-varying; multiple of 8), y = 128-col blocks.
// Same row-tile across col-blocks => block ids differ by gridDim.x (mult of 8)
// => same XCD => A rows L2-shared.
// EPI: 0 -> bf16 store (xp); 1 -> gelu(v+bias) -> u16 act; 2 -> v+bias -> f32 out
template <int EPI>
__global__ __launch_bounds__(256, 2) void k128_reg(
    const u16* __restrict__ Ahi, const u16* __restrict__ Alo,
    const u16* __restrict__ Wth, const u16* __restrict__ Wtl,
    const float* __restrict__ p0, u16* __restrict__ outu,
    float* __restrict__ outf, int ostride, int ntiles) {
  const int t = threadIdx.x, lane = t & 63, w = t >> 6;
  const int col0 = blockIdx.y * 128;
  const int wm0 = (w >> 1) * 32, wn0 = (w & 1) * 64;
  const int lc = lane & 15, lq = lane >> 4;
  const int lq8 = lq * 8, lq4 = lq * 4;

  // W fragments resident for this wave's 64-col slice: nf(4) x kchunk(4), hi+lo
  bf16x8 wh[4][4], wl[4][4];
  float bv[4];
#pragma unroll
  for (int nf = 0; nf < 4; nf++) {
    const int nr = col0 + wn0 + nf * 16 + lc;
    const u16* wr = Wth + (size_t)nr * 128;
    const u16* wr2 = Wtl + (size_t)nr * 128;
#pragma unroll
    for (int ks = 0; ks < 4; ks++) {
      wh[nf][ks] = *(const bf16x8*)(wr + ks * 32 + lq8);
      wl[nf][ks] = *(const bf16x8*)(wr2 + ks * 32 + lq8);
    }
    bv[nf] = (EPI == 0) ? 0.0f : p0[nr];
  }

  const f32x4 zz = {0.0f, 0.0f, 0.0f, 0.0f};
  for (int tile = blockIdx.x; tile < ntiles; tile += gridDim.x) {
    const int row0 = tile * 64;
    f32x4 acc[2][4];
#pragma unroll
    for (int mf = 0; mf < 2; mf++)
#pragma unroll
      for (int nf = 0; nf < 4; nf++) acc[mf][nf] = zz;
#pragma unroll
    for (int ks = 0; ks < 4; ks++) {
      bf16x8 ah[2], al[2];
#pragma unroll
      for (int mf = 0; mf < 2; mf++) {
        const size_t ao = (size_t)(row0 + wm0 + mf * 16 + lc) * 128 + ks * 32 + lq8;
        ah[mf] = *(const bf16x8*)(Ahi + ao);
        al[mf] = *(const bf16x8*)(Alo + ao);
      }
#pragma unroll
      for (int mf = 0; mf < 2; mf++)
#pragma unroll
        for (int nf = 0; nf < 4; nf++) {
          acc[mf][nf] = __builtin_amdgcn_mfma_f32_16x16x32_bf16(ah[mf], wh[nf][ks], acc[mf][nf], 0, 0, 0);
          acc[mf][nf] = __builtin_amdgcn_mfma_f32_16x16x32_bf16(ah[mf], wl[nf][ks], acc[mf][nf], 0, 0, 0);
          acc[mf][nf] = __builtin_amdgcn_mfma_f32_16x16x32_bf16(al[mf], wh[nf][ks], acc[mf][nf], 0, 0, 0);
        }
    }
#pragma unroll
    for (int mf = 0; mf < 2; mf++)
#pragma unroll
      for (int q = 0; q < 4; q++) {
        const int r = row0 + wm0 + mf * 16 + lq4 + q;
#pragma unroll
        for (int nf = 0; nf < 4; nf++) {
          const int col = col0 + wn0 + nf * 16 + lc;
          const size_t off = (size_t)r * ostride + col;
          const float v = acc[mf][nf][q];
          if (EPI == 0)      outu[off] = f2bf(v);
          else if (EPI == 1) outu[off] = f2bf(gelu_f(v + bv[nf]));
          else               outf[off] = v + bv[nf];
        }
      }
  }
}

// ---------------- w2 GEMM v3: h' = [h +] BN(act[M x K] @ W2[K x 128]) ----------------
// BM=64 (625 exact blocks), all 128 cols per block (act read ONCE).
// W2-hi double-buffered in LDS, BK=64 slabs (16 KB/buf, 64-window XOR swizzle);
// W2-lo direct from L2-hot global; act frags global->reg, prefetched 1 slab ahead.
// 4 waves 2x2, 1 barrier/iter. launch_bounds(256,3): 12 waves/CU.
template <int K, bool RES>
__global__ __launch_bounds__(256, 3) void gemm_w2(
    const u16* __restrict__ A, const u16* __restrict__ Wth,
    const u16* __restrict__ Wtl, const float* __restrict__ g,
    const float* __restrict__ bb, u16* __restrict__ hh, u16* __restrict__ hl) {
  __shared__ __align__(16) u16 Ws[2][128 * 64];   // [buf][n=128][k=64]
  const int t = threadIdx.x, lane = t & 63, w = t >> 6;
  const int row0 = blockIdx.x * 64;
  const int wm0 = (w >> 1) * 32, wn0 = (w & 1) * 64;
  const int lc = lane & 15, lq = lane >> 4;
  const int lq8 = lq * 8, lq4 = lq * 4;

  const f32x4 zz = {0.0f, 0.0f, 0.0f, 0.0f};
  f32x4 acc[2][4];
#pragma unroll
  for (int mf = 0; mf < 2; mf++)
#pragma unroll
    for (int nf = 0; nf < 4; nf++) acc[mf][nf] = zz;

  // stage W2-hi slab kb..kb+63 (all 128 n-rows) into lds buf
  auto stage_slab = [&](u16* lds, int kb) {
#pragma unroll
    for (int i = 0; i < 1024; i += 256) {       // 1024 chunks of 16B
      const int wc0 = i + w * 64;
      const int c = wc0 + lane;
      gl2lds(Wth + (size_t)(c >> 3) * K + kb + (c & 7) * 8, lds + wc0 * 8);
    }
  };
  auto load_af = [&](bf16x8 (&dst)[2][2], int kb) {
#pragma unroll
    for (int mf = 0; mf < 2; mf++)
#pragma unroll
      for (int ks = 0; ks < 2; ks++)
        dst[mf][ks] = *(const bf16x8*)(A + (size_t)(row0 + wm0 + mf * 16 + lc) * K +
                                       kb + ks * 32 + lq8);
  };

  bf16x8 afc[2][2], afn[2][2];
  stage_slab(Ws[0], 0);
  load_af(afc, 0);
  __syncthreads();

  constexpr int NT = K / 64;
#pragma unroll 2
  for (int tt = 0; tt < NT; tt++) {
    const int cur = tt & 1;
    if (tt + 1 < NT) {
      stage_slab(Ws[cur ^ 1], (tt + 1) * 64);   // async, flies under MFMA
      load_af(afn, (tt + 1) * 64);              // reg prefetch
    }
#pragma unroll
    for (int ks = 0; ks < 2; ks++) {
      bf16x8 whf[4], wlf[4];
#pragma unroll
      for (int nf = 0; nf < 4; nf++) {
        const int nr = wn0 + nf * 16 + lc;
        const int j = (ks * 32 + lq8) ^ ((nr & 7) << 3);
        whf[nf] = *(const bf16x8*)(Ws[cur] + nr * 64 + j);
        wlf[nf] = *(const bf16x8*)(Wtl + (size_t)nr * K + tt * 64 + j);
      }
#pragma unroll
      for (int mf = 0; mf < 2; mf++)
#pragma unroll
        for (int nf = 0; nf < 4; nf++) {
          acc[mf][nf] = __builtin_amdgcn_mfma_f32_16x16x32_bf16(afc[mf][ks], whf[nf], acc[mf][nf], 0, 0, 0);
          acc[mf][nf] = __builtin_amdgcn_mfma_f32_16x16x32_bf16(afc[mf][ks], wlf[nf], acc[mf][nf], 0, 0, 0);
        }
    }
    __syncthreads();   // drains next-slab stage; guards buf reuse
#pragma unroll
    for (int mf = 0; mf < 2; mf++)
#pragma unroll
      for (int ks = 0; ks < 2; ks++) afc[mf][ks] = afn[mf][ks];
  }

  float S0[4], S1[4];
#pragma unroll
  for (int nf = 0; nf < 4; nf++) {
    const int col = wn0 + nf * 16 + lc;
    S0[nf] = bnscale(g[col]);
    S1[nf] = bb[col];
  }
#pragma unroll
  for (int mf = 0; mf < 2; mf++)
#pragma unroll
    for (int q = 0; q < 4; q++) {
      const int r = row0 + wm0 + mf * 16 + lq4 + q;
#pragma unroll
      for (int nf = 0; nf < 4; nf++) {
        const int col = wn0 + nf * 16 + lc;
        const size_t off = (size_t)r * CH + col;
        float v = acc[mf][nf][q] * S0[nf] + S1[nf];
        if (RES) v += bf2f(hh[off]) + bf2f(hl[off]);
        u16 hi, lo; bf16split(v, hi, lo);
        hh[off] = hi; hl[off] = lo;
      }
    }
}

extern "C" void kernel_launch(void* const* d_in, const int* in_sizes, int n_in,
                              void* d_out, int out_size, void* d_ws, size_t ws_size,
                              hipStream_t stream) {
  const float* x    = (const float*)d_in[0];
  const float* xyz  = (const float*)d_in[1];
  const int*   knn  = (const int*)d_in[2];
  const float* sm   = (const float*)d_in[3];
  const float* scc  = (const float*)d_in[4];
  const float* shh  = (const float*)d_in[5];
  const float* bn0g = (const float*)d_in[6];
  const float* bn0b = (const float*)d_in[7];
  const float* nw1  = (const float*)d_in[8];
  const float* nb1  = (const float*)d_in[9];
  const float* nw2  = (const float*)d_in[10];
  const float* nbng = (const float*)d_in[11];
  const float* nbnb = (const float*)d_in[12];
  const float* lproj  = (const float*)d_in[13];
  const float* lcoor  = (const float*)d_in[14];
  const float* lscale = (const float*)d_in[15];
  const float* lbng   = (const float*)d_in[16];
  const float* lbnb   = (const float*)d_in[17];
  const float* mw1  = (const float*)d_in[18];
  const float* mb1  = (const float*)d_in[19];
  const float* mw2  = (const float*)d_in[20];
  const float* mbng = (const float*)d_in[21];
  const float* mbnb = (const float*)d_in[22];
  const float* pg   = (const float*)d_in[23];
  const float* pb   = (const float*)d_in[24];
  const float* pw   = (const float*)d_in[25];
  float* out = (float*)d_out;

  // workspace (bytes)
  char* ws = (char*)d_ws;
  u16*   h_hi = (u16*)(ws + 0);              // 10,240,000
  u16*   h_lo = (u16*)(ws + 10240000);       // 10,240,000
  u16*   act  = (u16*)(ws + 20480000);       // 40,960,000 (40000x512 bf16-hi)
  u16*   xp   = (u16*)(ws + 20480000);       // 10,240,000 (aliases act; never co-live)
  u16*   Wh   = (u16*)(ws + 61440000);       // 1,114,112
  u16*   Wl   = (u16*)(ws + 62554112);       // 1,114,112
  float* fb   = (float*)(ws + 63668224);     // 1,024

  const u16* nw1t   = Wh + 0;
  const u16* nw2t   = Wh + 32768;
  const u16* mw1t   = Wh + 65536;
  const u16* mw2t   = Wh + 262144;
  const u16* lprojt = Wh + 458752;
  const u16* postt  = Wh + 524288;
  const u16* nw1tl   = Wl + 0;
  const u16* nw2tl   = Wl + 32768;
  const u16* mw1tl   = Wl + 65536;
  const u16* mw2tl   = Wl + 262144;
  const u16* lprojtl = Wl + 458752;
  const u16* posttl  = Wl + 524288;

  prep_weights<<<2176, 256, 0, stream>>>(nw1, nw2, mw1, mw2, lproj, pw, pg, Wh, Wl);
  fold_pb<<<1, 256, 0, stream>>>(pw, pb, fb);

  spse_kernel<<<NPTS, 128, 0, stream>>>(x, xyz, knn, sm, scc, shh, bn0g, bn0b, h_hi, h_lo);

  // nbr_proj: act = gelu(nbr@w1+b1); h = BN(act@w2)
  k128_reg<1><<<dim3(256, 2), 256, 0, stream>>>(h_hi, h_lo, nw1t, nw1tl, nb1,
                                                act, nullptr, 256, 625);
  gemm_w2<256, false><<<625, 256, 0, stream>>>(act, nw2t, nw2tl, nbng, nbnb, h_hi, h_lo);

  // mlp 0 (residual)
  k128_reg<1><<<dim3(128, 4), 256, 0, stream>>>(h_hi, h_lo, mw1t, mw1tl, mb1,
                                                act, nullptr, 512, 625);
  gemm_w2<512, true><<<625, 256, 0, stream>>>(act, mw2t, mw2tl, mbng, mbnb, h_hi, h_lo);

  for (int i = 0; i < 4; i++) {
    k128_reg<0><<<dim3(625, 1), 256, 0, stream>>>(h_hi, h_lo, lprojt + i * 16384,
                                                  lprojtl + i * 16384, nullptr,
                                                  xp, nullptr, 128, 625);
    lfp_kernel<<<2500, 256, 0, stream>>>(xp, knn, xyz, lcoor + i * 96, lscale + i * 32,
                                         lbng + i * 128, lbnb + i * 128, h_hi, h_lo);
    if (i & 1) {
      const int j = i / 2 + 1;
      k128_reg<1><<<dim3(128, 4), 256, 0, stream>>>(h_hi, h_lo, mw1t + j * 65536,
                                                    mw1tl + j * 65536, mb1 + j * 512,
                                                    act, nullptr, 512, 625);
      gemm_w2<512, true><<<625, 256, 0, stream>>>(act, mw2t + j * 65536, mw2tl + j * 65536,
                                                  mbng + j * 128, mbnb + j * 128,
                                                  h_hi, h_lo);
    }
  }

  // postproj (BN folded into weights; rank-1 bias)
  k128_reg<2><<<dim3(256, 2), 256, 0, stream>>>(h_hi, h_lo, postt, posttl, fb,
                                                nullptr, out, 256, 625);
}